// Round 1
// baseline (280.669 us; speedup 1.0000x reference)
//
#include <hip/hip_runtime.h>
#include <hip/hip_bf16.h>

#define NEG 0.2f

typedef short bf16x8 __attribute__((ext_vector_type(8)));
typedef float floatx4 __attribute__((ext_vector_type(4)));

__device__ __forceinline__ float leaky(float v) { return v > 0.f ? v : NEG * v; }

__device__ __forceinline__ void unpack2(unsigned w, float& lo, float& hi) {
    union { unsigned u; float f; } a, b;
    a.u = w << 16;
    b.u = w & 0xffff0000u;
    lo = a.f; hi = b.f;
}

__device__ __forceinline__ unsigned short f2bf(float f) {
    union { float f; unsigned u; } v; v.f = f;
    unsigned r = v.u + 0x7fff + ((v.u >> 16) & 1);
    return (unsigned short)(r >> 16);
}

// ---------------- prelude: GAT1 transform + deg/pooled zero + W2 pack ------
// blocks [0, nTB): gat1_transform (16 nodes each)
// blocks [nTB, nTB+nZB): zero deg (+ block 0 zeroes pooled)
// block nTB+nZB: pack W2 into MFMA B-fragment layout
// All three roles touch disjoint memory; consumers are later launches.
__global__ void prelude(const float* __restrict__ x, const float* __restrict__ W1,
                        const float* __restrict__ as1, const float* __restrict__ ad1,
                        const float* __restrict__ W2,
                        __hip_bfloat16* __restrict__ h1b,
                        float* __restrict__ als1hm, float* __restrict__ ald1hm,
                        unsigned short* __restrict__ W2p,
                        int* __restrict__ deg, float* __restrict__ pooled,
                        int n, int nTB, int nZB) {
    __shared__ float xr[16][36];      // +4 pad keeps float4 stores aligned
    __shared__ float WaS[128];        // [j*4+h] = sum_c W1[j][h*64+c]*a_src[h][c]
    __shared__ float WaD[128];
    int b = blockIdx.x;
    int t = threadIdx.x;

    if (b >= nTB) {
        int zb = b - nTB;
        if (zb < nZB) {
            int i = zb * 256 + t;
            if (i < n) deg[i] = 0;
            if (zb == 0)
                for (int j = t; j < 64 * 32; j += 256) pooled[j] = 0.f;
        } else {
            // pack W2 [256,64] -> bf16 MFMA B fragments
            for (int idx = t; idx < 32 * 64; idx += 256) {
                int frag = idx >> 6, lane = idx & 63;
                int ct = frag >> 3, kt = frag & 7;
                int nn = ct * 16 + (lane & 15);
                int kb = kt * 32 + (lane >> 4) * 8;
#pragma unroll
                for (int j = 0; j < 8; j++)
                    W2p[frag * 512 + lane * 8 + j] = f2bf(W2[(kb + j) * 64 + nn]);
            }
        }
        return;
    }

    // ---- GAT1 transform: x[16,32] @ W1[32,256] -> h1b bf16 ----
    int base = b * 16;
    float w1r[32];
#pragma unroll
    for (int j = 0; j < 32; j++) w1r[j] = W1[j * 256 + t];
    if (t < 128) {
        int node = t >> 3, quad = t & 7;
        float4 v = make_float4(0.f, 0.f, 0.f, 0.f);
        if (base + node < n) v = ((const float4*)(x + (size_t)base * 32))[t];
        *((float4*)(&xr[node][quad * 4])) = v;
    }
    // rank-1 attention tables: WaS/WaD [32][4] (t<128: src half, t>=128: dst half)
    {
        int j = (t & 127) >> 2, h = t & 3;
        const float* av = (t < 128) ? as1 : ad1;
        float s_ = 0.f;
#pragma unroll 8
        for (int c = 0; c < 64; c++) s_ += W1[j * 256 + h * 64 + c] * av[h * 64 + c];
        if (t < 128) WaS[t] = s_; else WaD[t - 128] = s_;
    }
    __syncthreads();

    for (int nn = 0; nn < 16; nn++) {
        int node = base + nn;
        float acc0 = 0.f, acc1 = 0.f, acc2 = 0.f, acc3 = 0.f;
#pragma unroll
        for (int j = 0; j < 32; j += 4) {
            acc0 += xr[nn][j]     * w1r[j];
            acc1 += xr[nn][j + 1] * w1r[j + 1];
            acc2 += xr[nn][j + 2] * w1r[j + 2];
            acc3 += xr[nn][j + 3] * w1r[j + 3];
        }
        float acc = (acc0 + acc1) + (acc2 + acc3);
        if (node < n) h1b[(size_t)node * 256 + t] = __float2bfloat16(acc);
    }
    // per-node attention logits via 32-dot against WaS/WaD (no shuffles)
    if (t < 128) {
        int node = t >> 3, r = t & 7, h = r >> 1, sd = r & 1;
        int gnode = base + node;
        if (gnode < n) {
            const float* cf = sd ? WaD : WaS;
            float d_ = 0.f;
#pragma unroll
            for (int j = 0; j < 32; j++) d_ += xr[node][j] * cf[j * 4 + h];
            if (sd == 0) als1hm[(size_t)h * n + gnode] = d_;
            else         ald1hm[(size_t)h * n + gnode] = d_;
        }
    }
}

// ---------------- CSR build ----------------
__global__ void count_edges(const int* __restrict__ ei, int E, int n, int* deg) {
    int i = blockIdx.x * blockDim.x + threadIdx.x;
    int tot = E + n;
    if (i < tot) {
        int dst = (i < E) ? ei[E + i] : (i - E);
        atomicAdd(&deg[dst], 1);
    }
}

// single-block fused: dinv + exclusive scan -> rowptr/cursor (replaces 3 kernels)
__global__ __launch_bounds__(1024) void csr_scan(const int* __restrict__ deg,
                                                 float* __restrict__ dinv,
                                                 int* __restrict__ rowptr,
                                                 int* __restrict__ cursor, int n) {
    __shared__ unsigned short dl[20480];   // degrees fit u16 easily
    __shared__ int ws[1024];
    int t = threadIdx.x;
    int per = (n + 1023) >> 10;            // 20 for n=20000
    int cap = per << 10;
    // coalesced int4 staging of deg -> LDS u16, and write dinv on the fly
    for (int i = t * 4; i < cap; i += 4096) {
        int4 v;
        if (i + 3 < n) v = *((const int4*)(deg + i));
        else v = make_int4(i < n ? deg[i] : 0, i + 1 < n ? deg[i + 1] : 0,
                           i + 2 < n ? deg[i + 2] : 0, i + 3 < n ? deg[i + 3] : 0);
        dl[i] = (unsigned short)v.x; dl[i + 1] = (unsigned short)v.y;
        dl[i + 2] = (unsigned short)v.z; dl[i + 3] = (unsigned short)v.w;
        if (i < n)     dinv[i]     = rsqrtf(fmaxf((float)v.x, 1.0f));
        if (i + 1 < n) dinv[i + 1] = rsqrtf(fmaxf((float)v.y, 1.0f));
        if (i + 2 < n) dinv[i + 2] = rsqrtf(fmaxf((float)v.z, 1.0f));
        if (i + 3 < n) dinv[i + 3] = rsqrtf(fmaxf((float)v.w, 1.0f));
    }
    __syncthreads();
    int begin = t * per;
    int s = 0;
#pragma unroll
    for (int k = 0; k < 20; k++) s += dl[begin + k];
    ws[t] = s;
    __syncthreads();
    for (int off = 1; off < 1024; off <<= 1) {
        int v = (t >= off) ? ws[t - off] : 0;
        __syncthreads();
        ws[t] += v;
        __syncthreads();
    }
    int run = ws[t] - s;                    // exclusive prefix
#pragma unroll
    for (int k = 0; k < 20; k++) {
        int i = begin + k;
        if (i < n) { rowptr[i] = run; cursor[i] = run; run += dl[i]; }
    }
    if (t == 1023) rowptr[n] = ws[1023];
}

// slim CSR fill: only col scatter (edge weights now computed inline downstream)
__global__ void fill_edges(const int* __restrict__ ei, int E, int n, int* cursor,
                           int* __restrict__ col) {
    int i = blockIdx.x * blockDim.x + threadIdx.x;
    int tot = E + n;
    if (i < tot) {
        int src, dst;
        if (i < E) { src = ei[i]; dst = ei[E + i]; }
        else { src = i - E; dst = i - E; }
        int pos = atomicAdd(&cursor[dst], 1);
        col[pos] = src;
    }
}

// XCD-aware head partitioning (R13 win): block = ONE head x 4 dsts; head =
// (blockIdx&7)>>1 pins each head's 2.56 MB h1b slice into 2 XCDs' L2.
// Edge weight computed inline: exp(leaky(als1hm[h][src] + ald1hm[h][dst])).
__global__ void gat1_aggregate(const unsigned short* __restrict__ h1b,
                               const float* __restrict__ als1hm,
                               const float* __restrict__ ald1hm,
                               const int* __restrict__ rowptr,
                               const int* __restrict__ col, const float* __restrict__ b1,
                               unsigned short* __restrict__ out1b, int n) {
    int head = (blockIdx.x & 7) >> 1;
    int quad = (blockIdx.x >> 3) * 2 + (blockIdx.x & 1);
    int w = threadIdx.x >> 6, lane = threadIdx.x & 63;
    int dst = quad * 4 + w;
    if (dst >= n) return;
    int start = rowptr[dst], end = rowptr[dst + 1];
    const float* alsh = als1hm + (size_t)head * n;
    float a_d = ald1hm[(size_t)head * n + dst];

    int eg = lane >> 3;
    int cl = lane & 7;
    float acc[8];
#pragma unroll
    for (int j = 0; j < 8; j++) acc[j] = 0.f;
    float wsum = 0.f;
    for (int ib = start; ib < end; ib += 16) {
        int i0 = ib + eg, i1 = ib + 8 + eg;
        float w0 = 0.f, w1 = 0.f;
        int s0 = 0, s1 = 0;
        if (i0 < end) { s0 = col[i0]; w0 = __expf(leaky(alsh[s0] + a_d)); }
        if (i1 < end) { s1 = col[i1]; w1 = __expf(leaky(alsh[s1] + a_d)); }
        uint4 hv0 = *((const uint4*)(h1b + (size_t)s0 * 256 + head * 64) + cl);
        uint4 hv1 = *((const uint4*)(h1b + (size_t)s1 * 256 + head * 64) + cl);
        wsum += w0 + w1;
        float l0, u0, l1, u1, l2, u2, l3, u3;
        unpack2(hv0.x, l0, u0); unpack2(hv0.y, l1, u1);
        unpack2(hv0.z, l2, u2); unpack2(hv0.w, l3, u3);
        acc[0] += l0 * w0; acc[1] += u0 * w0;
        acc[2] += l1 * w0; acc[3] += u1 * w0;
        acc[4] += l2 * w0; acc[5] += u2 * w0;
        acc[6] += l3 * w0; acc[7] += u3 * w0;
        unpack2(hv1.x, l0, u0); unpack2(hv1.y, l1, u1);
        unpack2(hv1.z, l2, u2); unpack2(hv1.w, l3, u3);
        acc[0] += l0 * w1; acc[1] += u0 * w1;
        acc[2] += l1 * w1; acc[3] += u1 * w1;
        acc[4] += l2 * w1; acc[5] += u2 * w1;
        acc[6] += l3 * w1; acc[7] += u3 * w1;
    }
#pragma unroll
    for (int off = 8; off <= 32; off <<= 1) {
        wsum += __shfl_xor(wsum, off);
#pragma unroll
        for (int j = 0; j < 8; j++) acc[j] += __shfl_xor(acc[j], off);
    }
    float inv = 1.0f / (wsum + 1e-16f);
    if (lane < 8) {
        const float* bb = b1 + head * 64 + cl * 8;
        unsigned short pk[8];
#pragma unroll
        for (int j = 0; j < 8; j++) pk[j] = f2bf(fmaxf(acc[j] * inv + bb[j], 0.f));
        *((uint4*)(out1b + (size_t)dst * 256 + head * 64 + cl * 8)) = *(const uint4*)pk;
    }
}

// ---------------- GAT2 transform via MFMA 16x16x32 bf16 ----------------
__global__ void gat2_mfma(const unsigned short* __restrict__ out1b,
                          const unsigned short* __restrict__ W2p,
                          const float* __restrict__ asr, const float* __restrict__ adt,
                          __hip_bfloat16* __restrict__ h2b, float* __restrict__ als,
                          float* __restrict__ ald, int n) {
    __shared__ unsigned short xs[16 * 264];
    __shared__ float aps[4][16];
    __shared__ float apd[4][16];
    int t = threadIdx.x;
    int w = t >> 6, lane = t & 63;
    int base = blockIdx.x * 16;
    for (int i = t; i < 512; i += 256) {
        int nn = i >> 5, c = i & 31;
        uint4 v = make_uint4(0u, 0u, 0u, 0u);
        if (base + nn < n) v = *((const uint4*)(out1b + (size_t)(base + nn) * 256 + c * 8));
        *((uint4*)(xs + nn * 264 + c * 8)) = v;
    }
    __syncthreads();

    int m = lane & 15, quad = lane >> 4;
    floatx4 acc = {0.f, 0.f, 0.f, 0.f};
#pragma unroll
    for (int kt = 0; kt < 8; kt++) {
        bf16x8 a = *((const bf16x8*)(xs + m * 264 + kt * 32 + quad * 8));
        bf16x8 b = *((const bf16x8*)(W2p + (w * 8 + kt) * 512 + lane * 8));
        acc = __builtin_amdgcn_mfma_f32_16x16x32_bf16(a, b, acc, 0, 0, 0);
    }
    int colg = w * 16 + m;
    float a_s = asr[colg], a_d = adt[colg];
    float ps[4], pd[4];
#pragma unroll
    for (int q = 0; q < 4; q++) {
        int node = base + quad * 4 + q;
        if (node < n) h2b[(size_t)node * 64 + colg] = __float2bfloat16(acc[q]);
        ps[q] = acc[q] * a_s;
        pd[q] = acc[q] * a_d;
#pragma unroll
        for (int off = 1; off <= 8; off <<= 1) {
            ps[q] += __shfl_xor(ps[q], off);
            pd[q] += __shfl_xor(pd[q], off);
        }
        if (m == 0) {
            aps[w][quad * 4 + q] = ps[q];
            apd[w][quad * 4 + q] = pd[q];
        }
    }
    __syncthreads();
    if (t < 16 && base + t < n) {
        als[base + t] = aps[0][t] + aps[1][t] + aps[2][t] + aps[3][t];
        ald[base + t] = apd[0][t] + apd[1][t] + apd[2][t] + apd[3][t];
    }
}

// wave per dst; GAT2 aggregate FUSED with GCN transform. Edge weight computed
// inline from als2[src] + ald2[dst] (ald2[dst] wave-uniform).
__global__ void gat2_agg_gcn(const unsigned short* __restrict__ h2b,
                             const float* __restrict__ als2,
                             const float* __restrict__ ald2,
                             const int* __restrict__ rowptr,
                             const int* __restrict__ col, const float* __restrict__ b2,
                             const float* __restrict__ Wg,
                             float* __restrict__ h3, int n) {
    __shared__ float WgL[64 * 32];     // 8 KB
    __shared__ float h2L[4][64];       // 1 KB, per-wave slot
    int t = threadIdx.x;
    for (int i = t; i < 64 * 32; i += 256) WgL[i] = Wg[i];
    __syncthreads();

    int w = t >> 6, lane = t & 63;
    int dst = blockIdx.x * 4 + w;
    if (dst >= n) return;
    int start = rowptr[dst], end = rowptr[dst + 1];
    float a_d = ald2[dst];

    int eg = lane >> 3;
    int cl = lane & 7;
    float acc[8];
#pragma unroll
    for (int j = 0; j < 8; j++) acc[j] = 0.f;
    float wsum = 0.f;
    for (int ib = start; ib < end; ib += 8) {
        int i = ib + eg;
        float wv = 0.f;
        int s = 0;
        if (i < end) {
            s = col[i];
            wv = __expf(leaky(als2[s] + a_d));
        }
        wsum += wv;
        uint4 hv = *((const uint4*)(h2b + (size_t)s * 64) + cl);
        float l0, u0, l1, u1, l2, u2, l3, u3;
        unpack2(hv.x, l0, u0); unpack2(hv.y, l1, u1);
        unpack2(hv.z, l2, u2); unpack2(hv.w, l3, u3);
        acc[0] += l0 * wv; acc[1] += u0 * wv;
        acc[2] += l1 * wv; acc[3] += u1 * wv;
        acc[4] += l2 * wv; acc[5] += u2 * wv;
        acc[6] += l3 * wv; acc[7] += u3 * wv;
    }
#pragma unroll
    for (int off = 8; off <= 32; off <<= 1) {
        wsum += __shfl_xor(wsum, off);
#pragma unroll
        for (int j = 0; j < 8; j++) acc[j] += __shfl_xor(acc[j], off);
    }
    float inv = 1.0f / (wsum + 1e-16f);
    // relu(h2f) -> per-wave LDS (lanes 0..7 hold channels cl*8..cl*8+7)
    if (lane < 8) {
        const float* bb = b2 + cl * 8;
#pragma unroll
        for (int j = 0; j < 8; j++)
            h2L[w][cl * 8 + j] = fmaxf(acc[j] * inv + bb[j], 0.f);
    }
    // within-wave LDS write->read: compiler inserts lgkmcnt wait; no barrier needed
    if (lane < 32) {
        float s0 = 0.f, s1 = 0.f;
#pragma unroll
        for (int k = 0; k < 64; k += 2) {
            s0 += h2L[w][k]     * WgL[k * 32 + lane];
            s1 += h2L[w][k + 1] * WgL[(k + 1) * 32 + lane];
        }
        h3[(size_t)dst * 32 + lane] = s0 + s1;
    }
}

// wave per dst; GCN aggregate FUSED with mean-pool accumulation.
// norm computed inline from dinv; relu rows merged across the block's 4
// consecutive dsts (batch sorted => usually one graph) then atomically
// flushed into pooled (raw sums; head divides by binary-searched counts).
__global__ void gcn_agg_pool(const float* __restrict__ h3, const float* __restrict__ dinv,
                             const int* __restrict__ rowptr, const int* __restrict__ col,
                             const float* __restrict__ bg, const int* __restrict__ batch,
                             float* __restrict__ pooled, int n) {
    __shared__ float rowL[4][32];
    __shared__ int gL[4];
    int t = threadIdx.x;
    int w = t >> 6, lane = t & 63;
    int dst = blockIdx.x * 4 + w;
    bool act = dst < n;
    if (act) {
        int start = rowptr[dst], end = rowptr[dst + 1];
        float dv = dinv[dst];
        int eg = lane >> 3;
        int cl = lane & 7;
        float4 acc = make_float4(0.f, 0.f, 0.f, 0.f);
        for (int ib = start; ib < end; ib += 8) {
            int i = ib + eg;
            float nrm = 0.f;
            int s = 0;
            if (i < end) {
                s = col[i];
                nrm = dinv[s] * dv;
            }
            float4 hv = ((const float4*)(h3 + (size_t)s * 32))[cl];
            acc.x += hv.x * nrm; acc.y += hv.y * nrm;
            acc.z += hv.z * nrm; acc.w += hv.w * nrm;
        }
#pragma unroll
        for (int off = 8; off <= 32; off <<= 1) {
            acc.x += __shfl_xor(acc.x, off);
            acc.y += __shfl_xor(acc.y, off);
            acc.z += __shfl_xor(acc.z, off);
            acc.w += __shfl_xor(acc.w, off);
        }
        if (lane == 0) gL[w] = batch[dst];
        if (lane < 8) {
            int cl2 = lane & 7;
            float4 bb = ((const float4*)bg)[cl2];
            float4 o;
            o.x = fmaxf(acc.x + bb.x, 0.f);
            o.y = fmaxf(acc.y + bb.y, 0.f);
            o.z = fmaxf(acc.z + bb.z, 0.f);
            o.w = fmaxf(acc.w + bb.w, 0.f);
            *((float4*)&rowL[w][cl2 * 4]) = o;
        }
    } else if (lane == 0) {
        gL[w] = -1;
    }
    __syncthreads();
    if (t < 32) {
        float cur = 0.f; int curg = -1;
#pragma unroll
        for (int r = 0; r < 4; r++) {
            int g = gL[r];
            if (g < 0) continue;
            float v = rowL[r][t];
            if (g == curg) cur += v;
            else {
                if (curg >= 0) atomicAdd(&pooled[curg * 32 + t], cur);
                curg = g; cur = v;
            }
        }
        if (curg >= 0) atomicAdd(&pooled[curg * 32 + t], cur);
    }
}

// ---------------- head: pooled sums -> mean -> anomaly[64] + emb[64,64] ----
__device__ __forceinline__ int lbound(const int* __restrict__ b, int n, int key) {
    int lo = 0, hi = n;
    while (lo < hi) { int m = (lo + hi) >> 1; if (b[m] < key) lo = m + 1; else hi = m; }
    return lo;
}

__global__ void head_kernel(const float* __restrict__ pooled_s,
                            const int* __restrict__ batch, int n,
                            const float* __restrict__ A1, const float* __restrict__ ba1,
                            const float* __restrict__ A2, const float* __restrict__ ba2,
                            const float* __restrict__ A3, const float* __restrict__ ba3,
                            const float* __restrict__ Wemb, const float* __restrict__ bemb,
                            float* __restrict__ out) {
    __shared__ float P[64 * 32];
    __shared__ float Z1[64 * 32];
    __shared__ float Z2[64 * 16];
    __shared__ int cntL[64];
    int t = threadIdx.x;
    if (t < 64) cntL[t] = lbound(batch, n, t + 1) - lbound(batch, n, t);
    __syncthreads();
    for (int i = t; i < 64 * 32; i += 256) {
        int g = i >> 5;
        P[i] = pooled_s[i] / fmaxf((float)cntL[g], 1.0f);
    }
    __syncthreads();
    for (int i = t; i < 64 * 32; i += 256) {
        int g = i >> 5, c = i & 31;
        float a = ba1[c];
#pragma unroll
        for (int k = 0; k < 32; k++) a += P[g * 32 + k] * A1[k * 32 + c];
        Z1[i] = a > 0.f ? a : 0.f;
    }
    __syncthreads();
    for (int i = t; i < 64 * 16; i += 256) {
        int g = i >> 4, c = i & 15;
        float a = ba2[c];
#pragma unroll
        for (int k = 0; k < 32; k++) a += Z1[g * 32 + k] * A2[k * 16 + c];
        Z2[i] = a > 0.f ? a : 0.f;
    }
    __syncthreads();
    for (int g = t; g < 64; g += 256) {
        float a = ba3[0];
#pragma unroll
        for (int k = 0; k < 16; k++) a += Z2[g * 16 + k] * A3[k];
        out[g] = 1.0f / (1.0f + expf(-a));
    }
    for (int i = t; i < 64 * 64; i += 256) {
        int g = i >> 6, c = i & 63;
        float a = bemb[c];
#pragma unroll
        for (int k = 0; k < 32; k++) a += P[g * 32 + k] * Wemb[k * 64 + c];
        out[64 + i] = tanhf(a);
    }
}

extern "C" void kernel_launch(void* const* d_in, const int* in_sizes, int n_in,
                              void* d_out, int out_size, void* d_ws, size_t ws_size,
                              hipStream_t stream) {
    const float* x    = (const float*)d_in[0];
    const int*   ei   = (const int*)d_in[1];
    const int*   batch= (const int*)d_in[2];
    const float* W1   = (const float*)d_in[3];
    const float* as1  = (const float*)d_in[4];
    const float* ad1  = (const float*)d_in[5];
    const float* b1   = (const float*)d_in[6];
    const float* W2   = (const float*)d_in[7];
    const float* as2  = (const float*)d_in[8];
    const float* ad2  = (const float*)d_in[9];
    const float* b2   = (const float*)d_in[10];
    const float* Wg   = (const float*)d_in[11];
    const float* bg   = (const float*)d_in[12];
    const float* A1   = (const float*)d_in[13];
    const float* ba1  = (const float*)d_in[14];
    const float* A2   = (const float*)d_in[15];
    const float* ba2  = (const float*)d_in[16];
    const float* A3   = (const float*)d_in[17];
    const float* ba3  = (const float*)d_in[18];
    const float* Wemb = (const float*)d_in[19];
    const float* bemb = (const float*)d_in[20];
    float* out = (float*)d_out;

    const int N = in_sizes[0] / 32;
    const int E = in_sizes[1] / 2;
    const int ET = E + N;

    char* base = (char*)d_ws;
    size_t off = 0;
    auto take = [&](size_t bytes) -> char* {
        char* p = base + off;
        off = (off + bytes + 255) & ~(size_t)255;
        return p;
    };
    int*   deg    = (int*)take((size_t)N * 4);
    int*   rowptr = (int*)take((size_t)(N + 1) * 4);
    int*   cursor = (int*)take((size_t)N * 4);
    int*   col    = (int*)take((size_t)ET * 4);
    float* dinv   = (float*)take((size_t)N * 4);
    float* als1hm = (float*)take((size_t)N * 16);   // head-major [4][N]
    float* ald1hm = (float*)take((size_t)N * 16);
    unsigned short* W2p = (unsigned short*)take(32 * 512 * 2);
    char*  big1   = take((size_t)N * 512);          // h1b bf16; later h2b/h3/als2/ald2
    char*  big2   = take((size_t)N * 512);          // out1b bf16
    float* pooled = (float*)take(64 * 32 * 4);

    __hip_bfloat16* h1b = (__hip_bfloat16*)big1;
    __hip_bfloat16* h2b = (__hip_bfloat16*)big1;                  // after h1b dead
    float* h3   = (float*)(big1 + (size_t)N * 128);               // N*128 B
    float* als2 = (float*)(big1 + (size_t)N * 384);
    float* ald2 = (float*)(big1 + (size_t)N * 388);
    unsigned short* out1b = (unsigned short*)big2;                // N*512 B

    int gE = (ET + 255) / 256;
    int gN4 = (N + 3) / 4;
    int gN16 = (N + 15) / 16;
    int gZ = (N + 255) / 256;
    int nquads = (N + 3) / 4;
    int gAgg1 = ((nquads + 1) / 2) * 8;
    int gPre = gN16 + gZ + 1;

    prelude<<<gPre, 256, 0, stream>>>(x, W1, as1, ad1, W2, h1b, als1hm, ald1hm,
                                      W2p, deg, pooled, N, gN16, gZ);
    count_edges<<<gE, 256, 0, stream>>>(ei, E, N, deg);
    csr_scan<<<1, 1024, 0, stream>>>(deg, dinv, rowptr, cursor, N);
    fill_edges<<<gE, 256, 0, stream>>>(ei, E, N, cursor, col);
    gat1_aggregate<<<gAgg1, 256, 0, stream>>>((const unsigned short*)h1b, als1hm,
                                              ald1hm, rowptr, col, b1, out1b, N);

    gat2_mfma<<<gN16, 256, 0, stream>>>(out1b, W2p, as2, ad2, h2b, als2, ald2, N);
    gat2_agg_gcn<<<gN4, 256, 0, stream>>>((const unsigned short*)h2b, als2, ald2,
                                          rowptr, col, b2, Wg, h3, N);

    gcn_agg_pool<<<gN4, 256, 0, stream>>>(h3, dinv, rowptr, col, bg, batch,
                                          pooled, N);
    head_kernel<<<1, 256, 0, stream>>>(pooled, batch, N, A1, ba1, A2, ba2, A3, ba3,
                                       Wemb, bemb, out);
}

// Round 2
// 257.449 us; speedup vs baseline: 1.0902x; 1.0902x over previous
//
#include <hip/hip_runtime.h>
#include <hip/hip_bf16.h>

#define NEG 0.2f

typedef short bf16x8 __attribute__((ext_vector_type(8)));
typedef float floatx4 __attribute__((ext_vector_type(4)));

__device__ __forceinline__ float leaky(float v) { return v > 0.f ? v : NEG * v; }

__device__ __forceinline__ void unpack2(unsigned w, float& lo, float& hi) {
    union { unsigned u; float f; } a, b;
    a.u = w << 16;
    b.u = w & 0xffff0000u;
    lo = a.f; hi = b.f;
}

__device__ __forceinline__ unsigned short f2bf(float f) {
    union { float f; unsigned u; } v; v.f = f;
    unsigned r = v.u + 0x7fff + ((v.u >> 16) & 1);
    return (unsigned short)(r >> 16);
}

// ---------------- prelude: GAT1 transform + deg/pooled zero + W2 pack ------
// blocks [0, nTB): gat1_transform (16 nodes each)
// blocks [nTB, nTB+nZB): zero deg (+ block 0 zeroes pooled)
// block nTB+nZB: pack W2 into MFMA B-fragment layout
__global__ void prelude(const float* __restrict__ x, const float* __restrict__ W1,
                        const float* __restrict__ as1, const float* __restrict__ ad1,
                        const float* __restrict__ W2,
                        __hip_bfloat16* __restrict__ h1b,
                        float* __restrict__ als1, float* __restrict__ ald1,
                        unsigned short* __restrict__ W2p,
                        int* __restrict__ deg, float* __restrict__ pooled,
                        int n, int nTB, int nZB) {
    __shared__ float xr[16][36];      // +4 pad keeps float4 stores aligned
    __shared__ float WaS[128];        // [j*4+h] = sum_c W1[j][h*64+c]*a_src[h][c]
    __shared__ float WaD[128];
    int b = blockIdx.x;
    int t = threadIdx.x;

    if (b >= nTB) {
        int zb = b - nTB;
        if (zb < nZB) {
            int i = zb * 256 + t;
            if (i < n) deg[i] = 0;
            if (zb == 0)
                for (int j = t; j < 64 * 32; j += 256) pooled[j] = 0.f;
        } else {
            // pack W2 [256,64] -> bf16 MFMA B fragments
            for (int idx = t; idx < 32 * 64; idx += 256) {
                int frag = idx >> 6, lane = idx & 63;
                int ct = frag >> 3, kt = frag & 7;
                int nn = ct * 16 + (lane & 15);
                int kb = kt * 32 + (lane >> 4) * 8;
#pragma unroll
                for (int j = 0; j < 8; j++)
                    W2p[frag * 512 + lane * 8 + j] = f2bf(W2[(kb + j) * 64 + nn]);
            }
        }
        return;
    }

    // ---- GAT1 transform: x[16,32] @ W1[32,256] -> h1b bf16 ----
    int base = b * 16;
    float w1r[32];
#pragma unroll
    for (int j = 0; j < 32; j++) w1r[j] = W1[j * 256 + t];
    if (t < 128) {
        int node = t >> 3, quad = t & 7;
        float4 v = make_float4(0.f, 0.f, 0.f, 0.f);
        if (base + node < n) v = ((const float4*)(x + (size_t)base * 32))[t];
        *((float4*)(&xr[node][quad * 4])) = v;
    }
    // rank-1 attention tables: WaS/WaD [32][4] (t<128: src half, t>=128: dst half)
    {
        int j = (t & 127) >> 2, h = t & 3;
        const float* av = (t < 128) ? as1 : ad1;
        float s_ = 0.f;
#pragma unroll 8
        for (int c = 0; c < 64; c++) s_ += W1[j * 256 + h * 64 + c] * av[h * 64 + c];
        if (t < 128) WaS[t] = s_; else WaD[t - 128] = s_;
    }
    __syncthreads();

    for (int nn = 0; nn < 16; nn++) {
        int node = base + nn;
        float acc0 = 0.f, acc1 = 0.f, acc2 = 0.f, acc3 = 0.f;
#pragma unroll
        for (int j = 0; j < 32; j += 4) {
            acc0 += xr[nn][j]     * w1r[j];
            acc1 += xr[nn][j + 1] * w1r[j + 1];
            acc2 += xr[nn][j + 2] * w1r[j + 2];
            acc3 += xr[nn][j + 3] * w1r[j + 3];
        }
        float acc = (acc0 + acc1) + (acc2 + acc3);
        if (node < n) h1b[(size_t)node * 256 + t] = __float2bfloat16(acc);
    }
    // per-node attention logits via 32-dot against WaS/WaD (node-major [n][4])
    if (t < 128) {
        int node = t >> 3, r = t & 7, h = r >> 1, sd = r & 1;
        int gnode = base + node;
        if (gnode < n) {
            const float* cf = sd ? WaD : WaS;
            float d_ = 0.f;
#pragma unroll
            for (int j = 0; j < 32; j++) d_ += xr[node][j] * cf[j * 4 + h];
            if (sd == 0) als1[(size_t)gnode * 4 + h] = d_;
            else         ald1[(size_t)gnode * 4 + h] = d_;
        }
    }
}

// ---------------- CSR build ----------------
__global__ void count_edges(const int* __restrict__ ei, int E, int n, int* deg) {
    int i = blockIdx.x * blockDim.x + threadIdx.x;
    int tot = E + n;
    if (i < tot) {
        int dst = (i < E) ? ei[E + i] : (i - E);
        atomicAdd(&deg[dst], 1);
    }
}

__global__ void deg_dinv_bsum(const int* __restrict__ deg, float* __restrict__ dinv,
                              int* __restrict__ bsum, int n) {
    __shared__ int red[256];
    int t = threadIdx.x;
    int i = blockIdx.x * 256 + t;
    int d = (i < n) ? deg[i] : 0;
    if (i < n) dinv[i] = rsqrtf(fmaxf((float)d, 1.0f));
    red[t] = d;
    __syncthreads();
    for (int off = 128; off; off >>= 1) {
        if (t < off) red[t] += red[t + off];
        __syncthreads();
    }
    if (t == 0) bsum[blockIdx.x] = red[0];
}

__global__ void scan_bsum(const int* __restrict__ bsum, int* __restrict__ boff,
                          int* __restrict__ rowptr, int nb, int n) {
    __shared__ int s[256];
    int t = threadIdx.x;
    int own = (t < nb) ? bsum[t] : 0;
    s[t] = own;
    __syncthreads();
    for (int off = 1; off < 256; off <<= 1) {
        int v = (t >= off) ? s[t - off] : 0;
        __syncthreads();
        s[t] += v;
        __syncthreads();
    }
    if (t < nb) boff[t] = s[t] - own;
    if (t == 255) rowptr[n] = s[255];
}

__global__ void write_rowptr(const int* __restrict__ deg, const int* __restrict__ boff,
                             int* __restrict__ rowptr, int* __restrict__ cursor, int n) {
    __shared__ int s[256];
    int t = threadIdx.x;
    int i = blockIdx.x * 256 + t;
    int d = (i < n) ? deg[i] : 0;
    s[t] = d;
    __syncthreads();
    for (int off = 1; off < 256; off <<= 1) {
        int v = (t >= off) ? s[t - off] : 0;
        __syncthreads();
        s[t] += v;
        __syncthreads();
    }
    if (i < n) {
        int r = boff[blockIdx.x] + s[t] - d;
        rowptr[i] = r;
        cursor[i] = r;
    }
}

// CSR fill + GAT1 edge-weight precompute (4 heads). This kernel is
// atomic-latency-bound, so the exp work here is effectively free and keeps
// the issue-bound aggregator lean.
__global__ void fill_edges(const int* __restrict__ ei, int E, int n, int* cursor,
                           int* __restrict__ col, float* __restrict__ ew4,
                           const float* __restrict__ als1, const float* __restrict__ ald1) {
    int i = blockIdx.x * blockDim.x + threadIdx.x;
    int tot = E + n;
    if (i < tot) {
        int src, dst;
        if (i < E) { src = ei[i]; dst = ei[E + i]; }
        else { src = i - E; dst = i - E; }
        int pos = atomicAdd(&cursor[dst], 1);
        col[pos] = src;
        float4 as = ((const float4*)als1)[src];
        float4 ad = ((const float4*)ald1)[dst];
        float4 w;
        w.x = __expf(leaky(as.x + ad.x));
        w.y = __expf(leaky(as.y + ad.y));
        w.z = __expf(leaky(as.z + ad.z));
        w.w = __expf(leaky(as.w + ad.w));
        ((float4*)ew4)[pos] = w;
    }
}

// dst-per-wave, ALL 4 heads: 32 ch-lanes (8 ch each = full 256-ch row) x
// 2 edge-groups, unrolled 2x (4 edges in flight). vs the old (dst,head)
// layout this quarters the wave count and epilogue work at identical
// gather volume (each edge's full 512B h1 row, coalesced by 32 lanes).
__global__ void gat1_aggregate(const unsigned short* __restrict__ h1b,
                               const float* __restrict__ ew4,
                               const int* __restrict__ rowptr,
                               const int* __restrict__ col, const float* __restrict__ b1,
                               unsigned short* __restrict__ out1b, int n) {
    int w = threadIdx.x >> 6, lane = threadIdx.x & 63;
    int dst = blockIdx.x * 4 + w;
    if (dst >= n) return;
    int start = rowptr[dst], end = rowptr[dst + 1];
    int eg = lane >> 5;            // edge group 0/1
    int cl = lane & 31;            // channel-lane: ch cl*8..cl*8+7
    int head = cl >> 3;            // head owning those channels

    float acc[8];
#pragma unroll
    for (int j = 0; j < 8; j++) acc[j] = 0.f;
    float wsum = 0.f;
    for (int ib = start; ib < end; ib += 4) {
        int i0 = ib + eg, i1 = ib + 2 + eg;
        float w0 = 0.f, w1 = 0.f;
        int s0 = 0, s1 = 0;
        if (i0 < end) { s0 = col[i0]; w0 = ew4[i0 * 4 + head]; }
        if (i1 < end) { s1 = col[i1]; w1 = ew4[i1 * 4 + head]; }
        uint4 hv0 = *((const uint4*)(h1b + (size_t)s0 * 256) + cl);
        uint4 hv1 = *((const uint4*)(h1b + (size_t)s1 * 256) + cl);
        wsum += w0 + w1;
        float l0, u0, l1, u1, l2, u2, l3, u3;
        unpack2(hv0.x, l0, u0); unpack2(hv0.y, l1, u1);
        unpack2(hv0.z, l2, u2); unpack2(hv0.w, l3, u3);
        acc[0] += l0 * w0; acc[1] += u0 * w0;
        acc[2] += l1 * w0; acc[3] += u1 * w0;
        acc[4] += l2 * w0; acc[5] += u2 * w0;
        acc[6] += l3 * w0; acc[7] += u3 * w0;
        unpack2(hv1.x, l0, u0); unpack2(hv1.y, l1, u1);
        unpack2(hv1.z, l2, u2); unpack2(hv1.w, l3, u3);
        acc[0] += l0 * w1; acc[1] += u0 * w1;
        acc[2] += l1 * w1; acc[3] += u1 * w1;
        acc[4] += l2 * w1; acc[5] += u2 * w1;
        acc[6] += l3 * w1; acc[7] += u3 * w1;
    }
    // combine the two edge-groups; every lane of head h accumulated the same
    // per-edge weight, so wsum needs only the cross-group fold.
    wsum += __shfl_xor(wsum, 32);
#pragma unroll
    for (int j = 0; j < 8; j++) acc[j] += __shfl_xor(acc[j], 32);
    float inv = 1.0f / (wsum + 1e-16f);
    if (lane < 32) {
        const float* bb = b1 + lane * 8;
        unsigned short pk[8];
#pragma unroll
        for (int j = 0; j < 8; j++) pk[j] = f2bf(fmaxf(acc[j] * inv + bb[j], 0.f));
        *((uint4*)(out1b + (size_t)dst * 256 + lane * 8)) = *(const uint4*)pk;
    }
}

// ---------------- GAT2 transform via MFMA 16x16x32 bf16 ----------------
__global__ void gat2_mfma(const unsigned short* __restrict__ out1b,
                          const unsigned short* __restrict__ W2p,
                          const float* __restrict__ asr, const float* __restrict__ adt,
                          __hip_bfloat16* __restrict__ h2b, float* __restrict__ als,
                          float* __restrict__ ald, int n) {
    __shared__ unsigned short xs[16 * 264];
    __shared__ float aps[4][16];
    __shared__ float apd[4][16];
    int t = threadIdx.x;
    int w = t >> 6, lane = t & 63;
    int base = blockIdx.x * 16;
    for (int i = t; i < 512; i += 256) {
        int nn = i >> 5, c = i & 31;
        uint4 v = make_uint4(0u, 0u, 0u, 0u);
        if (base + nn < n) v = *((const uint4*)(out1b + (size_t)(base + nn) * 256 + c * 8));
        *((uint4*)(xs + nn * 264 + c * 8)) = v;
    }
    __syncthreads();

    int m = lane & 15, quad = lane >> 4;
    floatx4 acc = {0.f, 0.f, 0.f, 0.f};
#pragma unroll
    for (int kt = 0; kt < 8; kt++) {
        bf16x8 a = *((const bf16x8*)(xs + m * 264 + kt * 32 + quad * 8));
        bf16x8 b = *((const bf16x8*)(W2p + (w * 8 + kt) * 512 + lane * 8));
        acc = __builtin_amdgcn_mfma_f32_16x16x32_bf16(a, b, acc, 0, 0, 0);
    }
    int colg = w * 16 + m;
    float a_s = asr[colg], a_d = adt[colg];
    float ps[4], pd[4];
#pragma unroll
    for (int q = 0; q < 4; q++) {
        int node = base + quad * 4 + q;
        if (node < n) h2b[(size_t)node * 64 + colg] = __float2bfloat16(acc[q]);
        ps[q] = acc[q] * a_s;
        pd[q] = acc[q] * a_d;
#pragma unroll
        for (int off = 1; off <= 8; off <<= 1) {
            ps[q] += __shfl_xor(ps[q], off);
            pd[q] += __shfl_xor(pd[q], off);
        }
        if (m == 0) {
            aps[w][quad * 4 + q] = ps[q];
            apd[w][quad * 4 + q] = pd[q];
        }
    }
    __syncthreads();
    if (t < 16 && base + t < n) {
        als[base + t] = aps[0][t] + aps[1][t] + aps[2][t] + aps[3][t];
        ald[base + t] = apd[0][t] + apd[1][t] + apd[2][t] + apd[3][t];
    }
}

// wave per dst; GAT2 aggregate FUSED with GCN transform. Edge weight computed
// inline from als2[src] + ald2[dst] (ald2[dst] wave-uniform).
__global__ void gat2_agg_gcn(const unsigned short* __restrict__ h2b,
                             const float* __restrict__ als2,
                             const float* __restrict__ ald2,
                             const int* __restrict__ rowptr,
                             const int* __restrict__ col, const float* __restrict__ b2,
                             const float* __restrict__ Wg,
                             float* __restrict__ h3, int n) {
    __shared__ float WgL[64 * 32];     // 8 KB
    __shared__ float h2L[4][64];       // 1 KB, per-wave slot
    int t = threadIdx.x;
    for (int i = t; i < 64 * 32; i += 256) WgL[i] = Wg[i];
    __syncthreads();

    int w = t >> 6, lane = t & 63;
    int dst = blockIdx.x * 4 + w;
    if (dst >= n) return;
    int start = rowptr[dst], end = rowptr[dst + 1];
    float a_d = ald2[dst];

    int eg = lane >> 3;
    int cl = lane & 7;
    float acc[8];
#pragma unroll
    for (int j = 0; j < 8; j++) acc[j] = 0.f;
    float wsum = 0.f;
    for (int ib = start; ib < end; ib += 8) {
        int i = ib + eg;
        float wv = 0.f;
        int s = 0;
        if (i < end) {
            s = col[i];
            wv = __expf(leaky(als2[s] + a_d));
        }
        wsum += wv;
        uint4 hv = *((const uint4*)(h2b + (size_t)s * 64) + cl);
        float l0, u0, l1, u1, l2, u2, l3, u3;
        unpack2(hv.x, l0, u0); unpack2(hv.y, l1, u1);
        unpack2(hv.z, l2, u2); unpack2(hv.w, l3, u3);
        acc[0] += l0 * wv; acc[1] += u0 * wv;
        acc[2] += l1 * wv; acc[3] += u1 * wv;
        acc[4] += l2 * wv; acc[5] += u2 * wv;
        acc[6] += l3 * wv; acc[7] += u3 * wv;
    }
#pragma unroll
    for (int off = 8; off <= 32; off <<= 1) {
        wsum += __shfl_xor(wsum, off);
#pragma unroll
        for (int j = 0; j < 8; j++) acc[j] += __shfl_xor(acc[j], off);
    }
    float inv = 1.0f / (wsum + 1e-16f);
    // relu(h2f) -> per-wave LDS (lanes 0..7 hold channels cl*8..cl*8+7)
    if (lane < 8) {
        const float* bb = b2 + cl * 8;
#pragma unroll
        for (int j = 0; j < 8; j++)
            h2L[w][cl * 8 + j] = fmaxf(acc[j] * inv + bb[j], 0.f);
    }
    // within-wave LDS write->read: compiler inserts lgkmcnt wait; no barrier needed
    if (lane < 32) {
        float s0 = 0.f, s1 = 0.f;
#pragma unroll
        for (int k = 0; k < 64; k += 2) {
            s0 += h2L[w][k]     * WgL[k * 32 + lane];
            s1 += h2L[w][k + 1] * WgL[(k + 1) * 32 + lane];
        }
        h3[(size_t)dst * 32 + lane] = s0 + s1;
    }
}

// wave per dst; GCN aggregate FUSED with mean-pool accumulation.
// norm computed inline from dinv; relu rows merged across the block's 4
// consecutive dsts (batch sorted => usually one graph) then atomically
// flushed into pooled (raw sums; head divides by binary-searched counts).
__global__ void gcn_agg_pool(const float* __restrict__ h3, const float* __restrict__ dinv,
                             const int* __restrict__ rowptr, const int* __restrict__ col,
                             const float* __restrict__ bg, const int* __restrict__ batch,
                             float* __restrict__ pooled, int n) {
    __shared__ float rowL[4][32];
    __shared__ int gL[4];
    int t = threadIdx.x;
    int w = t >> 6, lane = t & 63;
    int dst = blockIdx.x * 4 + w;
    bool act = dst < n;
    if (act) {
        int start = rowptr[dst], end = rowptr[dst + 1];
        float dv = dinv[dst];
        int eg = lane >> 3;
        int cl = lane & 7;
        float4 acc = make_float4(0.f, 0.f, 0.f, 0.f);
        for (int ib = start; ib < end; ib += 8) {
            int i = ib + eg;
            float nrm = 0.f;
            int s = 0;
            if (i < end) {
                s = col[i];
                nrm = dinv[s] * dv;
            }
            float4 hv = ((const float4*)(h3 + (size_t)s * 32))[cl];
            acc.x += hv.x * nrm; acc.y += hv.y * nrm;
            acc.z += hv.z * nrm; acc.w += hv.w * nrm;
        }
#pragma unroll
        for (int off = 8; off <= 32; off <<= 1) {
            acc.x += __shfl_xor(acc.x, off);
            acc.y += __shfl_xor(acc.y, off);
            acc.z += __shfl_xor(acc.z, off);
            acc.w += __shfl_xor(acc.w, off);
        }
        if (lane == 0) gL[w] = batch[dst];
        if (lane < 8) {
            int cl2 = lane & 7;
            float4 bb = ((const float4*)bg)[cl2];
            float4 o;
            o.x = fmaxf(acc.x + bb.x, 0.f);
            o.y = fmaxf(acc.y + bb.y, 0.f);
            o.z = fmaxf(acc.z + bb.z, 0.f);
            o.w = fmaxf(acc.w + bb.w, 0.f);
            *((float4*)&rowL[w][cl2 * 4]) = o;
        }
    } else if (lane == 0) {
        gL[w] = -1;
    }
    __syncthreads();
    if (t < 32) {
        float cur = 0.f; int curg = -1;
#pragma unroll
        for (int r = 0; r < 4; r++) {
            int g = gL[r];
            if (g < 0) continue;
            float v = rowL[r][t];
            if (g == curg) cur += v;
            else {
                if (curg >= 0) atomicAdd(&pooled[curg * 32 + t], cur);
                curg = g; cur = v;
            }
        }
        if (curg >= 0) atomicAdd(&pooled[curg * 32 + t], cur);
    }
}

// ---------------- head: pooled sums -> mean -> anomaly[64] + emb[64,64] ----
__device__ __forceinline__ int lbound(const int* __restrict__ b, int n, int key) {
    int lo = 0, hi = n;
    while (lo < hi) { int m = (lo + hi) >> 1; if (b[m] < key) lo = m + 1; else hi = m; }
    return lo;
}

__global__ void head_kernel(const float* __restrict__ pooled_s,
                            const int* __restrict__ batch, int n,
                            const float* __restrict__ A1, const float* __restrict__ ba1,
                            const float* __restrict__ A2, const float* __restrict__ ba2,
                            const float* __restrict__ A3, const float* __restrict__ ba3,
                            const float* __restrict__ Wemb, const float* __restrict__ bemb,
                            float* __restrict__ out) {
    __shared__ float P[64 * 32];
    __shared__ float Z1[64 * 32];
    __shared__ float Z2[64 * 16];
    __shared__ int cntL[64];
    int t = threadIdx.x;
    if (t < 64) cntL[t] = lbound(batch, n, t + 1) - lbound(batch, n, t);
    __syncthreads();
    for (int i = t; i < 64 * 32; i += 256) {
        int g = i >> 5;
        P[i] = pooled_s[i] / fmaxf((float)cntL[g], 1.0f);
    }
    __syncthreads();
    for (int i = t; i < 64 * 32; i += 256) {
        int g = i >> 5, c = i & 31;
        float a = ba1[c];
#pragma unroll
        for (int k = 0; k < 32; k++) a += P[g * 32 + k] * A1[k * 32 + c];
        Z1[i] = a > 0.f ? a : 0.f;
    }
    __syncthreads();
    for (int i = t; i < 64 * 16; i += 256) {
        int g = i >> 4, c = i & 15;
        float a = ba2[c];
#pragma unroll
        for (int k = 0; k < 32; k++) a += Z1[g * 32 + k] * A2[k * 16 + c];
        Z2[i] = a > 0.f ? a : 0.f;
    }
    __syncthreads();
    for (int g = t; g < 64; g += 256) {
        float a = ba3[0];
#pragma unroll
        for (int k = 0; k < 16; k++) a += Z2[g * 16 + k] * A3[k];
        out[g] = 1.0f / (1.0f + expf(-a));
    }
    for (int i = t; i < 64 * 64; i += 256) {
        int g = i >> 6, c = i & 63;
        float a = bemb[c];
#pragma unroll
        for (int k = 0; k < 32; k++) a += P[g * 32 + k] * Wemb[k * 64 + c];
        out[64 + i] = tanhf(a);
    }
}

extern "C" void kernel_launch(void* const* d_in, const int* in_sizes, int n_in,
                              void* d_out, int out_size, void* d_ws, size_t ws_size,
                              hipStream_t stream) {
    const float* x    = (const float*)d_in[0];
    const int*   ei   = (const int*)d_in[1];
    const int*   batch= (const int*)d_in[2];
    const float* W1   = (const float*)d_in[3];
    const float* as1  = (const float*)d_in[4];
    const float* ad1  = (const float*)d_in[5];
    const float* b1   = (const float*)d_in[6];
    const float* W2   = (const float*)d_in[7];
    const float* as2  = (const float*)d_in[8];
    const float* ad2  = (const float*)d_in[9];
    const float* b2   = (const float*)d_in[10];
    const float* Wg   = (const float*)d_in[11];
    const float* bg   = (const float*)d_in[12];
    const float* A1   = (const float*)d_in[13];
    const float* ba1  = (const float*)d_in[14];
    const float* A2   = (const float*)d_in[15];
    const float* ba2  = (const float*)d_in[16];
    const float* A3   = (const float*)d_in[17];
    const float* ba3  = (const float*)d_in[18];
    const float* Wemb = (const float*)d_in[19];
    const float* bemb = (const float*)d_in[20];
    float* out = (float*)d_out;

    const int N = in_sizes[0] / 32;
    const int E = in_sizes[1] / 2;
    const int ET = E + N;

    char* base = (char*)d_ws;
    size_t off = 0;
    auto take = [&](size_t bytes) -> char* {
        char* p = base + off;
        off = (off + bytes + 255) & ~(size_t)255;
        return p;
    };
    int*   deg    = (int*)take((size_t)N * 4);
    int*   rowptr = (int*)take((size_t)(N + 1) * 4);
    int*   cursor = (int*)take((size_t)N * 4);
    int*   col    = (int*)take((size_t)ET * 4);
    float* ew4    = (float*)take((size_t)ET * 16);
    float* dinv   = (float*)take((size_t)N * 4);
    float* als1   = (float*)take((size_t)N * 16);   // node-major [n][4]
    float* ald1   = (float*)take((size_t)N * 16);
    int*   bsum   = (int*)take(256 * 4);
    int*   boff   = (int*)take(256 * 4);
    unsigned short* W2p = (unsigned short*)take(32 * 512 * 2);
    char*  big1   = take((size_t)N * 512);          // h1b bf16; later h2b/h3/als2/ald2
    char*  big2   = take((size_t)N * 512);          // out1b bf16
    float* pooled = (float*)take(64 * 32 * 4);

    __hip_bfloat16* h1b = (__hip_bfloat16*)big1;
    __hip_bfloat16* h2b = (__hip_bfloat16*)big1;                  // after h1b dead
    float* h3   = (float*)(big1 + (size_t)N * 128);               // N*128 B
    float* als2 = (float*)(big1 + (size_t)N * 384);
    float* ald2 = (float*)(big1 + (size_t)N * 388);
    unsigned short* out1b = (unsigned short*)big2;                // N*512 B

    int gN = (N + 255) / 256;
    int gE = (ET + 255) / 256;
    int gN4 = (N + 3) / 4;
    int gN16 = (N + 15) / 16;
    int gZ = (N + 255) / 256;
    int gPre = gN16 + gZ + 1;

    prelude<<<gPre, 256, 0, stream>>>(x, W1, as1, ad1, W2, h1b, als1, ald1,
                                      W2p, deg, pooled, N, gN16, gZ);
    count_edges<<<gE, 256, 0, stream>>>(ei, E, N, deg);
    deg_dinv_bsum<<<gN, 256, 0, stream>>>(deg, dinv, bsum, N);
    scan_bsum<<<1, 256, 0, stream>>>(bsum, boff, rowptr, gN, N);
    write_rowptr<<<gN, 256, 0, stream>>>(deg, boff, rowptr, cursor, N);
    fill_edges<<<gE, 256, 0, stream>>>(ei, E, N, cursor, col, ew4, als1, ald1);

    gat1_aggregate<<<gN4, 256, 0, stream>>>((const unsigned short*)h1b, ew4,
                                            rowptr, col, b1, out1b, N);

    gat2_mfma<<<gN16, 256, 0, stream>>>(out1b, W2p, as2, ad2, h2b, als2, ald2, N);
    gat2_agg_gcn<<<gN4, 256, 0, stream>>>((const unsigned short*)h2b, als2, ald2,
                                          rowptr, col, b2, Wg, h3, N);

    gcn_agg_pool<<<gN4, 256, 0, stream>>>(h3, dinv, rowptr, col, bg, batch,
                                          pooled, N);
    head_kernel<<<1, 256, 0, stream>>>(pooled, batch, N, A1, ba1, A2, ba2, A3, ba3,
                                       Wemb, bemb, out);
}

// Round 3
// 249.427 us; speedup vs baseline: 1.1253x; 1.0322x over previous
//
#include <hip/hip_runtime.h>
#include <hip/hip_bf16.h>

#define NEG 0.2f

typedef short bf16x8 __attribute__((ext_vector_type(8)));
typedef float floatx4 __attribute__((ext_vector_type(4)));

__device__ __forceinline__ float leaky(float v) { return v > 0.f ? v : NEG * v; }

__device__ __forceinline__ void unpack2(unsigned w, float& lo, float& hi) {
    union { unsigned u; float f; } a, b;
    a.u = w << 16;
    b.u = w & 0xffff0000u;
    lo = a.f; hi = b.f;
}

__device__ __forceinline__ unsigned short f2bf(float f) {
    union { float f; unsigned u; } v; v.f = f;
    unsigned r = v.u + 0x7fff + ((v.u >> 16) & 1);
    return (unsigned short)(r >> 16);
}

// ---------------- prelude: GAT1 transform + deg/pooled zero + W2 pack ------
__global__ void prelude(const float* __restrict__ x, const float* __restrict__ W1,
                        const float* __restrict__ as1, const float* __restrict__ ad1,
                        const float* __restrict__ W2,
                        __hip_bfloat16* __restrict__ h1b,
                        float* __restrict__ als1, float* __restrict__ ald1,
                        unsigned short* __restrict__ W2p,
                        int* __restrict__ deg, float* __restrict__ pooled,
                        int n, int nTB, int nZB) {
    __shared__ float xr[16][36];      // +4 pad keeps float4 stores aligned
    __shared__ float WaS[128];        // [j*4+h] = sum_c W1[j][h*64+c]*a_src[h][c]
    __shared__ float WaD[128];
    int b = blockIdx.x;
    int t = threadIdx.x;

    if (b >= nTB) {
        int zb = b - nTB;
        if (zb < nZB) {
            int i = zb * 256 + t;
            if (i < n) deg[i] = 0;
            if (zb == 0)
                for (int j = t; j < 64 * 32; j += 256) pooled[j] = 0.f;
        } else {
            // pack W2 [256,64] -> bf16 MFMA B fragments
            for (int idx = t; idx < 32 * 64; idx += 256) {
                int frag = idx >> 6, lane = idx & 63;
                int ct = frag >> 3, kt = frag & 7;
                int nn = ct * 16 + (lane & 15);
                int kb = kt * 32 + (lane >> 4) * 8;
#pragma unroll
                for (int j = 0; j < 8; j++)
                    W2p[frag * 512 + lane * 8 + j] = f2bf(W2[(kb + j) * 64 + nn]);
            }
        }
        return;
    }

    // ---- GAT1 transform: x[16,32] @ W1[32,256] -> h1b bf16 ----
    int base = b * 16;
    float w1r[32];
#pragma unroll
    for (int j = 0; j < 32; j++) w1r[j] = W1[j * 256 + t];
    if (t < 128) {
        int node = t >> 3, quad = t & 7;
        float4 v = make_float4(0.f, 0.f, 0.f, 0.f);
        if (base + node < n) v = ((const float4*)(x + (size_t)base * 32))[t];
        *((float4*)(&xr[node][quad * 4])) = v;
    }
    // rank-1 attention tables: WaS/WaD [32][4]
    {
        int j = (t & 127) >> 2, h = t & 3;
        const float* av = (t < 128) ? as1 : ad1;
        float s_ = 0.f;
#pragma unroll 8
        for (int c = 0; c < 64; c++) s_ += W1[j * 256 + h * 64 + c] * av[h * 64 + c];
        if (t < 128) WaS[t] = s_; else WaD[t - 128] = s_;
    }
    __syncthreads();

    for (int nn = 0; nn < 16; nn++) {
        int node = base + nn;
        float acc0 = 0.f, acc1 = 0.f, acc2 = 0.f, acc3 = 0.f;
#pragma unroll
        for (int j = 0; j < 32; j += 4) {
            acc0 += xr[nn][j]     * w1r[j];
            acc1 += xr[nn][j + 1] * w1r[j + 1];
            acc2 += xr[nn][j + 2] * w1r[j + 2];
            acc3 += xr[nn][j + 3] * w1r[j + 3];
        }
        float acc = (acc0 + acc1) + (acc2 + acc3);
        if (node < n) h1b[(size_t)node * 256 + t] = __float2bfloat16(acc);
    }
    // per-node attention logits via 32-dot against WaS/WaD (node-major [n][4])
    if (t < 128) {
        int node = t >> 3, r = t & 7, h = r >> 1, sd = r & 1;
        int gnode = base + node;
        if (gnode < n) {
            const float* cf = sd ? WaD : WaS;
            float d_ = 0.f;
#pragma unroll
            for (int j = 0; j < 32; j++) d_ += xr[node][j] * cf[j * 4 + h];
            if (sd == 0) als1[(size_t)gnode * 4 + h] = d_;
            else         ald1[(size_t)gnode * 4 + h] = d_;
        }
    }
}

// ---------------- CSR build ----------------
__global__ void count_edges(const int* __restrict__ ei, int E, int n, int* deg) {
    int i = blockIdx.x * blockDim.x + threadIdx.x;
    int tot = E + n;
    if (i < tot) {
        int dst = (i < E) ? ei[E + i] : (i - E);
        atomicAdd(&deg[dst], 1);
    }
}

__global__ void deg_dinv_bsum(const int* __restrict__ deg, float* __restrict__ dinv,
                              int* __restrict__ bsum, int n) {
    __shared__ int red[256];
    int t = threadIdx.x;
    int i = blockIdx.x * 256 + t;
    int d = (i < n) ? deg[i] : 0;
    if (i < n) dinv[i] = rsqrtf(fmaxf((float)d, 1.0f));
    red[t] = d;
    __syncthreads();
    for (int off = 128; off; off >>= 1) {
        if (t < off) red[t] += red[t + off];
        __syncthreads();
    }
    if (t == 0) bsum[blockIdx.x] = red[0];
}

// write_rowptr with INLINE bsum scan (each block redundantly scans <=256
// entries in LDS - replaces the separate scan_bsum launch).
__global__ void write_rowptr(const int* __restrict__ deg, const int* __restrict__ bsum,
                             int* __restrict__ rowptr, int* __restrict__ cursor,
                             int nb, int n) {
    __shared__ int s[256];
    __shared__ int boffL;
    int t = threadIdx.x;
    int own = (t < nb) ? bsum[t] : 0;
    s[t] = own;
    __syncthreads();
    for (int off = 1; off < 256; off <<= 1) {
        int v = (t >= off) ? s[t - off] : 0;
        __syncthreads();
        s[t] += v;
        __syncthreads();
    }
    if (t == blockIdx.x) boffL = s[t] - own;   // exclusive prefix for this block
    __syncthreads();

    int i = blockIdx.x * 256 + t;
    int d = (i < n) ? deg[i] : 0;
    s[t] = d;
    __syncthreads();
    for (int off = 1; off < 256; off <<= 1) {
        int v = (t >= off) ? s[t - off] : 0;
        __syncthreads();
        s[t] += v;
        __syncthreads();
    }
    if (i < n) {
        int r = boffL + s[t] - d;
        rowptr[i] = r;
        cursor[i] = r;
        if (i == n - 1) rowptr[n] = r + d;
    }
}

// CSR fill + GAT1 edge-weight precompute (4 heads). Atomic-latency-bound, so
// the exp work here is effectively free and keeps the aggregator lean.
__global__ void fill_edges(const int* __restrict__ ei, int E, int n, int* cursor,
                           int* __restrict__ col, float* __restrict__ ew4,
                           const float* __restrict__ als1, const float* __restrict__ ald1) {
    int i = blockIdx.x * blockDim.x + threadIdx.x;
    int tot = E + n;
    if (i < tot) {
        int src, dst;
        if (i < E) { src = ei[i]; dst = ei[E + i]; }
        else { src = i - E; dst = i - E; }
        int pos = atomicAdd(&cursor[dst], 1);
        col[pos] = src;
        float4 as = ((const float4*)als1)[src];
        float4 ad = ((const float4*)ald1)[dst];
        float4 w;
        w.x = __expf(leaky(as.x + ad.x));
        w.y = __expf(leaky(as.y + ad.y));
        w.z = __expf(leaky(as.z + ad.z));
        w.w = __expf(leaky(as.w + ad.w));
        ((float4*)ew4)[pos] = w;
    }
}

// ---------------- FUSED: GAT1 aggregate + GAT2 transform (MFMA) -------------
// Block = 16 dsts, 8 waves. Phase 1: each wave aggregates 2 dsts (32 ch-lanes
// x 2 edge-groups, 8 edges/iter = 4 gathers in flight) and writes the relu'd
// bf16 out1 row into the MFMA staging LDS. Phase 2: waves 0-3 run the
// 16x16x32 MFMA (out1[16,256] @ W2[256,64]) + GAT2 logit epilogue.
// Kills the 20MB out1b global round-trip and one launch.
__global__ __launch_bounds__(512) void gat1_agg_mfma(
        const unsigned short* __restrict__ h1b,
        const float* __restrict__ ew4,
        const int* __restrict__ rowptr, const int* __restrict__ col,
        const float* __restrict__ b1,
        const unsigned short* __restrict__ W2p,
        const float* __restrict__ asr, const float* __restrict__ adt,
        __hip_bfloat16* __restrict__ h2b,
        float* __restrict__ als, float* __restrict__ ald, int n) {
    __shared__ unsigned short xs[16 * 264];
    __shared__ float aps[4][16];
    __shared__ float apd[4][16];
    int t = threadIdx.x;              // 512 = 8 waves
    int w = t >> 6, lane = t & 63;
    int base = blockIdx.x * 16;

    // ---- phase 1: aggregation, 2 dsts per wave ----
    int eg = lane >> 5;               // edge group 0/1
    int cl = lane & 31;               // channel-lane: ch cl*8..cl*8+7
    int head = cl >> 3;
    for (int rep = 0; rep < 2; rep++) {
        int r = w * 2 + rep;
        int dst = base + r;
        if (dst < n) {
            int start = rowptr[dst], end = rowptr[dst + 1];
            float acc[8];
#pragma unroll
            for (int j = 0; j < 8; j++) acc[j] = 0.f;
            float wsum = 0.f;
            for (int ib = start; ib < end; ib += 8) {
                int ss[4]; float wv[4];
#pragma unroll
                for (int k = 0; k < 4; k++) {
                    int i = ib + 2 * k + eg;
                    bool vld = i < end;
                    ss[k] = vld ? col[i] : 0;
                    wv[k] = vld ? ew4[i * 4 + head] : 0.f;
                }
                uint4 hv[4];
#pragma unroll
                for (int k = 0; k < 4; k++)
                    hv[k] = *((const uint4*)(h1b + (size_t)ss[k] * 256) + cl);
                wsum += (wv[0] + wv[1]) + (wv[2] + wv[3]);
#pragma unroll
                for (int k = 0; k < 4; k++) {
                    float l0, u0, l1, u1, l2, u2, l3, u3;
                    unpack2(hv[k].x, l0, u0); unpack2(hv[k].y, l1, u1);
                    unpack2(hv[k].z, l2, u2); unpack2(hv[k].w, l3, u3);
                    float wk = wv[k];
                    acc[0] += l0 * wk; acc[1] += u0 * wk;
                    acc[2] += l1 * wk; acc[3] += u1 * wk;
                    acc[4] += l2 * wk; acc[5] += u2 * wk;
                    acc[6] += l3 * wk; acc[7] += u3 * wk;
                }
            }
            // fold the two edge-groups (same-head lanes carry identical wsum)
            wsum += __shfl_xor(wsum, 32);
#pragma unroll
            for (int j = 0; j < 8; j++) acc[j] += __shfl_xor(acc[j], 32);
            float inv = 1.0f / (wsum + 1e-16f);
            if (lane < 32) {
                const float* bb = b1 + cl * 8;
                unsigned short pk[8];
#pragma unroll
                for (int j = 0; j < 8; j++)
                    pk[j] = f2bf(fmaxf(acc[j] * inv + bb[j], 0.f));
                *((uint4*)(xs + r * 264 + cl * 8)) = *(const uint4*)pk;
            }
        }
    }
    __syncthreads();

    // ---- phase 2: MFMA out1[16,256] @ W2p -> h2 + logits (waves 0-3) ----
    if (w < 4) {
        int m = lane & 15, quad = lane >> 4;
        floatx4 acc = {0.f, 0.f, 0.f, 0.f};
#pragma unroll
        for (int kt = 0; kt < 8; kt++) {
            bf16x8 a = *((const bf16x8*)(xs + m * 264 + kt * 32 + quad * 8));
            bf16x8 b = *((const bf16x8*)(W2p + (w * 8 + kt) * 512 + lane * 8));
            acc = __builtin_amdgcn_mfma_f32_16x16x32_bf16(a, b, acc, 0, 0, 0);
        }
        int colg = w * 16 + m;
        float a_s = asr[colg], a_d = adt[colg];
        float ps[4], pd[4];
#pragma unroll
        for (int q = 0; q < 4; q++) {
            int node = base + quad * 4 + q;
            if (node < n) h2b[(size_t)node * 64 + colg] = __float2bfloat16(acc[q]);
            ps[q] = acc[q] * a_s;
            pd[q] = acc[q] * a_d;
#pragma unroll
            for (int off = 1; off <= 8; off <<= 1) {
                ps[q] += __shfl_xor(ps[q], off);
                pd[q] += __shfl_xor(pd[q], off);
            }
            if (m == 0) {
                aps[w][quad * 4 + q] = ps[q];
                apd[w][quad * 4 + q] = pd[q];
            }
        }
    }
    __syncthreads();
    if (t < 16 && base + t < n) {
        als[base + t] = aps[0][t] + aps[1][t] + aps[2][t] + aps[3][t];
        ald[base + t] = apd[0][t] + apd[1][t] + apd[2][t] + apd[3][t];
    }
}

// wave per dst; GAT2 aggregate FUSED with GCN transform; 2x unrolled loop.
__global__ void gat2_agg_gcn(const unsigned short* __restrict__ h2b,
                             const float* __restrict__ als2,
                             const float* __restrict__ ald2,
                             const int* __restrict__ rowptr,
                             const int* __restrict__ col, const float* __restrict__ b2,
                             const float* __restrict__ Wg,
                             float* __restrict__ h3, int n) {
    __shared__ float WgL[64 * 32];     // 8 KB
    __shared__ float h2L[4][64];       // 1 KB, per-wave slot
    int t = threadIdx.x;
    for (int i = t; i < 64 * 32; i += 256) WgL[i] = Wg[i];
    __syncthreads();

    int w = t >> 6, lane = t & 63;
    int dst = blockIdx.x * 4 + w;
    if (dst >= n) return;
    int start = rowptr[dst], end = rowptr[dst + 1];
    float a_d = ald2[dst];

    int eg = lane >> 3;
    int cl = lane & 7;
    float acc[8];
#pragma unroll
    for (int j = 0; j < 8; j++) acc[j] = 0.f;
    float wsum = 0.f;
    for (int ib = start; ib < end; ib += 16) {
        int i0 = ib + eg, i1 = ib + 8 + eg;
        float w0 = 0.f, w1 = 0.f;
        int s0 = 0, s1 = 0;
        if (i0 < end) { s0 = col[i0]; w0 = __expf(leaky(als2[s0] + a_d)); }
        if (i1 < end) { s1 = col[i1]; w1 = __expf(leaky(als2[s1] + a_d)); }
        uint4 hv0 = *((const uint4*)(h2b + (size_t)s0 * 64) + cl);
        uint4 hv1 = *((const uint4*)(h2b + (size_t)s1 * 64) + cl);
        wsum += w0 + w1;
        float l0, u0, l1, u1, l2, u2, l3, u3;
        unpack2(hv0.x, l0, u0); unpack2(hv0.y, l1, u1);
        unpack2(hv0.z, l2, u2); unpack2(hv0.w, l3, u3);
        acc[0] += l0 * w0; acc[1] += u0 * w0;
        acc[2] += l1 * w0; acc[3] += u1 * w0;
        acc[4] += l2 * w0; acc[5] += u2 * w0;
        acc[6] += l3 * w0; acc[7] += u3 * w0;
        unpack2(hv1.x, l0, u0); unpack2(hv1.y, l1, u1);
        unpack2(hv1.z, l2, u2); unpack2(hv1.w, l3, u3);
        acc[0] += l0 * w1; acc[1] += u0 * w1;
        acc[2] += l1 * w1; acc[3] += u1 * w1;
        acc[4] += l2 * w1; acc[5] += u2 * w1;
        acc[6] += l3 * w1; acc[7] += u3 * w1;
    }
#pragma unroll
    for (int off = 8; off <= 32; off <<= 1) {
        wsum += __shfl_xor(wsum, off);
#pragma unroll
        for (int j = 0; j < 8; j++) acc[j] += __shfl_xor(acc[j], off);
    }
    float inv = 1.0f / (wsum + 1e-16f);
    if (lane < 8) {
        const float* bb = b2 + cl * 8;
#pragma unroll
        for (int j = 0; j < 8; j++)
            h2L[w][cl * 8 + j] = fmaxf(acc[j] * inv + bb[j], 0.f);
    }
    if (lane < 32) {
        float s0 = 0.f, s1 = 0.f;
#pragma unroll
        for (int k = 0; k < 64; k += 2) {
            s0 += h2L[w][k]     * WgL[k * 32 + lane];
            s1 += h2L[w][k + 1] * WgL[(k + 1) * 32 + lane];
        }
        h3[(size_t)dst * 32 + lane] = s0 + s1;
    }
}

// wave per dst; GCN aggregate FUSED with mean-pool accumulation; 2x unrolled.
__global__ void gcn_agg_pool(const float* __restrict__ h3, const float* __restrict__ dinv,
                             const int* __restrict__ rowptr, const int* __restrict__ col,
                             const float* __restrict__ bg, const int* __restrict__ batch,
                             float* __restrict__ pooled, int n) {
    __shared__ float rowL[4][32];
    __shared__ int gL[4];
    int t = threadIdx.x;
    int w = t >> 6, lane = t & 63;
    int dst = blockIdx.x * 4 + w;
    bool act = dst < n;
    if (act) {
        int start = rowptr[dst], end = rowptr[dst + 1];
        float dv = dinv[dst];
        int eg = lane >> 3;
        int cl = lane & 7;
        float4 acc = make_float4(0.f, 0.f, 0.f, 0.f);
        for (int ib = start; ib < end; ib += 16) {
            int i0 = ib + eg, i1 = ib + 8 + eg;
            float n0 = 0.f, n1 = 0.f;
            int s0 = 0, s1 = 0;
            if (i0 < end) { s0 = col[i0]; n0 = dinv[s0] * dv; }
            if (i1 < end) { s1 = col[i1]; n1 = dinv[s1] * dv; }
            float4 hv0 = ((const float4*)(h3 + (size_t)s0 * 32))[cl];
            float4 hv1 = ((const float4*)(h3 + (size_t)s1 * 32))[cl];
            acc.x += hv0.x * n0; acc.y += hv0.y * n0;
            acc.z += hv0.z * n0; acc.w += hv0.w * n0;
            acc.x += hv1.x * n1; acc.y += hv1.y * n1;
            acc.z += hv1.z * n1; acc.w += hv1.w * n1;
        }
#pragma unroll
        for (int off = 8; off <= 32; off <<= 1) {
            acc.x += __shfl_xor(acc.x, off);
            acc.y += __shfl_xor(acc.y, off);
            acc.z += __shfl_xor(acc.z, off);
            acc.w += __shfl_xor(acc.w, off);
        }
        if (lane == 0) gL[w] = batch[dst];
        if (lane < 8) {
            int cl2 = lane & 7;
            float4 bb = ((const float4*)bg)[cl2];
            float4 o;
            o.x = fmaxf(acc.x + bb.x, 0.f);
            o.y = fmaxf(acc.y + bb.y, 0.f);
            o.z = fmaxf(acc.z + bb.z, 0.f);
            o.w = fmaxf(acc.w + bb.w, 0.f);
            *((float4*)&rowL[w][cl2 * 4]) = o;
        }
    } else if (lane == 0) {
        gL[w] = -1;
    }
    __syncthreads();
    if (t < 32) {
        float cur = 0.f; int curg = -1;
#pragma unroll
        for (int r = 0; r < 4; r++) {
            int g = gL[r];
            if (g < 0) continue;
            float v = rowL[r][t];
            if (g == curg) cur += v;
            else {
                if (curg >= 0) atomicAdd(&pooled[curg * 32 + t], cur);
                curg = g; cur = v;
            }
        }
        if (curg >= 0) atomicAdd(&pooled[curg * 32 + t], cur);
    }
}

// ---------------- head: pooled sums -> mean -> anomaly[64] + emb[64,64] ----
__device__ __forceinline__ int lbound(const int* __restrict__ b, int n, int key) {
    int lo = 0, hi = n;
    while (lo < hi) { int m = (lo + hi) >> 1; if (b[m] < key) lo = m + 1; else hi = m; }
    return lo;
}

__global__ void head_kernel(const float* __restrict__ pooled_s,
                            const int* __restrict__ batch, int n,
                            const float* __restrict__ A1, const float* __restrict__ ba1,
                            const float* __restrict__ A2, const float* __restrict__ ba2,
                            const float* __restrict__ A3, const float* __restrict__ ba3,
                            const float* __restrict__ Wemb, const float* __restrict__ bemb,
                            float* __restrict__ out) {
    __shared__ float P[64 * 32];
    __shared__ float Z1[64 * 32];
    __shared__ float Z2[64 * 16];
    __shared__ int cntL[64];
    int t = threadIdx.x;
    if (t < 64) cntL[t] = lbound(batch, n, t + 1) - lbound(batch, n, t);
    __syncthreads();
    for (int i = t; i < 64 * 32; i += 256) {
        int g = i >> 5;
        P[i] = pooled_s[i] / fmaxf((float)cntL[g], 1.0f);
    }
    __syncthreads();
    for (int i = t; i < 64 * 32; i += 256) {
        int g = i >> 5, c = i & 31;
        float a = ba1[c];
#pragma unroll
        for (int k = 0; k < 32; k++) a += P[g * 32 + k] * A1[k * 32 + c];
        Z1[i] = a > 0.f ? a : 0.f;
    }
    __syncthreads();
    for (int i = t; i < 64 * 16; i += 256) {
        int g = i >> 4, c = i & 15;
        float a = ba2[c];
#pragma unroll
        for (int k = 0; k < 32; k++) a += Z1[g * 32 + k] * A2[k * 16 + c];
        Z2[i] = a > 0.f ? a : 0.f;
    }
    __syncthreads();
    for (int g = t; g < 64; g += 256) {
        float a = ba3[0];
#pragma unroll
        for (int k = 0; k < 16; k++) a += Z2[g * 16 + k] * A3[k];
        out[g] = 1.0f / (1.0f + expf(-a));
    }
    for (int i = t; i < 64 * 64; i += 256) {
        int g = i >> 6, c = i & 63;
        float a = bemb[c];
#pragma unroll
        for (int k = 0; k < 32; k++) a += P[g * 32 + k] * Wemb[k * 64 + c];
        out[64 + i] = tanhf(a);
    }
}

extern "C" void kernel_launch(void* const* d_in, const int* in_sizes, int n_in,
                              void* d_out, int out_size, void* d_ws, size_t ws_size,
                              hipStream_t stream) {
    const float* x    = (const float*)d_in[0];
    const int*   ei   = (const int*)d_in[1];
    const int*   batch= (const int*)d_in[2];
    const float* W1   = (const float*)d_in[3];
    const float* as1  = (const float*)d_in[4];
    const float* ad1  = (const float*)d_in[5];
    const float* b1   = (const float*)d_in[6];
    const float* W2   = (const float*)d_in[7];
    const float* as2  = (const float*)d_in[8];
    const float* ad2  = (const float*)d_in[9];
    const float* b2   = (const float*)d_in[10];
    const float* Wg   = (const float*)d_in[11];
    const float* bg   = (const float*)d_in[12];
    const float* A1   = (const float*)d_in[13];
    const float* ba1  = (const float*)d_in[14];
    const float* A2   = (const float*)d_in[15];
    const float* ba2  = (const float*)d_in[16];
    const float* A3   = (const float*)d_in[17];
    const float* ba3  = (const float*)d_in[18];
    const float* Wemb = (const float*)d_in[19];
    const float* bemb = (const float*)d_in[20];
    float* out = (float*)d_out;

    const int N = in_sizes[0] / 32;
    const int E = in_sizes[1] / 2;
    const int ET = E + N;

    char* base = (char*)d_ws;
    size_t off = 0;
    auto take = [&](size_t bytes) -> char* {
        char* p = base + off;
        off = (off + bytes + 255) & ~(size_t)255;
        return p;
    };
    int*   deg    = (int*)take((size_t)N * 4);
    int*   rowptr = (int*)take((size_t)(N + 1) * 4);
    int*   cursor = (int*)take((size_t)N * 4);
    int*   col    = (int*)take((size_t)ET * 4);
    float* ew4    = (float*)take((size_t)ET * 16);
    float* dinv   = (float*)take((size_t)N * 4);
    float* als1   = (float*)take((size_t)N * 16);   // node-major [n][4]
    float* ald1   = (float*)take((size_t)N * 16);
    int*   bsum   = (int*)take(256 * 4);
    unsigned short* W2p = (unsigned short*)take(32 * 512 * 2);
    char*  big1   = take((size_t)N * 512);          // h1b bf16; later h3
    char*  big2   = take((size_t)N * 512);          // h2b + als2/ald2
    float* pooled = (float*)take(64 * 32 * 4);

    __hip_bfloat16* h1b = (__hip_bfloat16*)big1;
    float* h3   = (float*)(big1 + (size_t)N * 128);               // after h1b dead
    // h2b/als2/ald2 live in big2: written by gat1_agg_mfma WHILE h1b (big1)
    // is still being gathered - must not alias big1.
    __hip_bfloat16* h2b = (__hip_bfloat16*)big2;                  // N*128 B
    float* als2 = (float*)(big2 + (size_t)N * 128);
    float* ald2 = (float*)(big2 + (size_t)N * 132);

    int gN = (N + 255) / 256;
    int gE = (ET + 255) / 256;
    int gN4 = (N + 3) / 4;
    int gN16 = (N + 15) / 16;
    int gZ = (N + 255) / 256;
    int gPre = gN16 + gZ + 1;

    prelude<<<gPre, 256, 0, stream>>>(x, W1, as1, ad1, W2, h1b, als1, ald1,
                                      W2p, deg, pooled, N, gN16, gZ);
    count_edges<<<gE, 256, 0, stream>>>(ei, E, N, deg);
    deg_dinv_bsum<<<gN, 256, 0, stream>>>(deg, dinv, bsum, N);
    write_rowptr<<<gN, 256, 0, stream>>>(deg, bsum, rowptr, cursor, gN, N);
    fill_edges<<<gE, 256, 0, stream>>>(ei, E, N, cursor, col, ew4, als1, ald1);

    gat1_agg_mfma<<<gN16, 512, 0, stream>>>((const unsigned short*)h1b, ew4,
                                            rowptr, col, b1, W2p, as2, ad2,
                                            h2b, als2, ald2, N);

    gat2_agg_gcn<<<gN4, 256, 0, stream>>>((const unsigned short*)h2b, als2, ald2,
                                          rowptr, col, b2, Wg, h3, N);
    gcn_agg_pool<<<gN4, 256, 0, stream>>>(h3, dinv, rowptr, col, bg, batch,
                                          pooled, N);
    head_kernel<<<1, 256, 0, stream>>>(pooled, batch, N, A1, ba1, A2, ba2, A3, ba3,
                                       Wemb, bemb, out);
}

// Round 4
// 237.924 us; speedup vs baseline: 1.1797x; 1.0483x over previous
//
#include <hip/hip_runtime.h>
#include <hip/hip_bf16.h>

#define NEG 0.2f

typedef short bf16x8 __attribute__((ext_vector_type(8)));
typedef float floatx4 __attribute__((ext_vector_type(4)));

__device__ __forceinline__ float leaky(float v) { return v > 0.f ? v : NEG * v; }

__device__ __forceinline__ void unpack2(unsigned w, float& lo, float& hi) {
    union { unsigned u; float f; } a, b;
    a.u = w << 16;
    b.u = w & 0xffff0000u;
    lo = a.f; hi = b.f;
}

__device__ __forceinline__ unsigned short f2bf(float f) {
    union { float f; unsigned u; } v; v.f = f;
    unsigned r = v.u + 0x7fff + ((v.u >> 16) & 1);
    return (unsigned short)(r >> 16);
}

// ---------------- prelude: logits + x->bf16 + deg/pooled zero + W pack -----
// blocks [0, nTB): 64 nodes each: attention logits (rank-1) + xb conversion
// blocks [nTB, nTB+nZB): zero deg (+ block 0 zeroes pooled)
// block nTB+nZB: pack W2 and W1 into MFMA B-fragment layouts
// NOTE: h = x@W1 is never materialized anymore (aggregation moved to x-space).
__global__ void prelude(const float* __restrict__ x, const float* __restrict__ W1,
                        const float* __restrict__ as1, const float* __restrict__ ad1,
                        const float* __restrict__ W2,
                        unsigned* __restrict__ xbu,          // [n][16] packed bf16x2
                        float* __restrict__ als1, float* __restrict__ ald1,
                        unsigned short* __restrict__ W2p,
                        unsigned short* __restrict__ W1p,
                        int* __restrict__ deg, float* __restrict__ pooled,
                        int n, int nTB, int nZB) {
    __shared__ float xr[64][36];      // stride 36: 16B-aligned float4 rows
    __shared__ float WaS[128];        // [j*4+h] = sum_c W1[j][h*64+c]*a_src[h][c]
    __shared__ float WaD[128];
    int b = blockIdx.x;
    int t = threadIdx.x;

    if (b >= nTB) {
        int zb = b - nTB;
        if (zb < nZB) {
            int i = zb * 256 + t;
            if (i < n) deg[i] = 0;
            if (zb == 0)
                for (int j = t; j < 64 * 32; j += 256) pooled[j] = 0.f;
        } else {
            // pack W2 [256,64] -> bf16 MFMA B fragments (K=32 tiles x 8)
            for (int idx = t; idx < 32 * 64; idx += 256) {
                int frag = idx >> 6, lane = idx & 63;
                int ct = frag >> 3, kt = frag & 7;
                int nn = ct * 16 + (lane & 15);
                int kb = kt * 32 + (lane >> 4) * 8;
#pragma unroll
                for (int j = 0; j < 8; j++)
                    W2p[frag * 512 + lane * 8 + j] = f2bf(W2[(kb + j) * 64 + nn]);
            }
            // pack W1 [32,256] -> per-head B fragments: frag = h*4+nt,
            // B[k][n]: k = x-channel (0..31), n = out-ch h*64+nt*16+col
            for (int idx = t; idx < 16 * 512; idx += 256) {
                int frag = idx >> 9;
                int h = frag >> 2, nt = frag & 3;
                int pos = idx & 511;
                int lane = pos >> 3, j = pos & 7;
                int coln = lane & 15, quad = lane >> 4;
                int k = quad * 8 + j;
                W1p[idx] = f2bf(W1[k * 256 + h * 64 + nt * 16 + coln]);
            }
        }
        return;
    }

    // ---- 64 nodes: stage x, rank-1 logit tables, logits, xb bf16 ----
    int base = b * 64;
    for (int rep = 0; rep < 2; rep++) {
        int s = t + 256 * rep;            // float4 slot 0..511
        int node = s >> 3, quad = s & 7;
        float4 v = make_float4(0.f, 0.f, 0.f, 0.f);
        if (base + node < n) v = ((const float4*)(x + (size_t)base * 32))[s];
        *((float4*)(&xr[node][quad * 4])) = v;
    }
    {
        int j = (t & 127) >> 2, h = t & 3;
        const float* av = (t < 128) ? as1 : ad1;
        float s_ = 0.f;
#pragma unroll 8
        for (int c = 0; c < 64; c++) s_ += W1[j * 256 + h * 64 + c] * av[h * 64 + c];
        if (t < 128) WaS[t] = s_; else WaD[t - 128] = s_;
    }
    __syncthreads();

    // logits: 64 nodes x 4 heads x {src,dst} = 512 32-dots
    for (int rep = 0; rep < 2; rep++) {
        int q = t + 256 * rep;
        int node = q >> 3, r = q & 7, h = r >> 1, sd = r & 1;
        int gnode = base + node;
        if (gnode < n) {
            const float* cf = sd ? WaD : WaS;
            float d_ = 0.f;
#pragma unroll
            for (int j = 0; j < 32; j++) d_ += xr[node][j] * cf[j * 4 + h];
            if (sd == 0) als1[(size_t)gnode * 4 + h] = d_;
            else         ald1[(size_t)gnode * 4 + h] = d_;
        }
    }
    // xb: bf16 x rows (the new gather target - 1.25 MB, L2-resident)
    for (int rep = 0; rep < 4; rep++) {
        int i = t + 256 * rep;            // 0..1023 = 64 nodes x 16 pairs
        int node = i >> 4, cp = i & 15;
        int gnode = base + node;
        if (gnode < n) {
            unsigned short u0 = f2bf(xr[node][cp * 2]);
            unsigned short u1 = f2bf(xr[node][cp * 2 + 1]);
            xbu[(size_t)gnode * 16 + cp] = ((unsigned)u1 << 16) | u0;
        }
    }
}

// ---------------- CSR build ----------------
__global__ void count_edges(const int* __restrict__ ei, int E, int n, int* deg) {
    int i = blockIdx.x * blockDim.x + threadIdx.x;
    int tot = E + n;
    if (i < tot) {
        int dst = (i < E) ? ei[E + i] : (i - E);
        atomicAdd(&deg[dst], 1);
    }
}

__global__ void deg_dinv_bsum(const int* __restrict__ deg, float* __restrict__ dinv,
                              int* __restrict__ bsum, int n) {
    __shared__ int red[256];
    int t = threadIdx.x;
    int i = blockIdx.x * 256 + t;
    int d = (i < n) ? deg[i] : 0;
    if (i < n) dinv[i] = rsqrtf(fmaxf((float)d, 1.0f));
    red[t] = d;
    __syncthreads();
    for (int off = 128; off; off >>= 1) {
        if (t < off) red[t] += red[t + off];
        __syncthreads();
    }
    if (t == 0) bsum[blockIdx.x] = red[0];
}

// write_rowptr with INLINE bsum scan (each block redundantly scans <=256
// entries in LDS).
__global__ void write_rowptr(const int* __restrict__ deg, const int* __restrict__ bsum,
                             int* __restrict__ rowptr, int* __restrict__ cursor,
                             int nb, int n) {
    __shared__ int s[256];
    __shared__ int boffL;
    int t = threadIdx.x;
    int own = (t < nb) ? bsum[t] : 0;
    s[t] = own;
    __syncthreads();
    for (int off = 1; off < 256; off <<= 1) {
        int v = (t >= off) ? s[t - off] : 0;
        __syncthreads();
        s[t] += v;
        __syncthreads();
    }
    if (t == blockIdx.x) boffL = s[t] - own;
    __syncthreads();

    int i = blockIdx.x * 256 + t;
    int d = (i < n) ? deg[i] : 0;
    s[t] = d;
    __syncthreads();
    for (int off = 1; off < 256; off <<= 1) {
        int v = (t >= off) ? s[t - off] : 0;
        __syncthreads();
        s[t] += v;
        __syncthreads();
    }
    if (i < n) {
        int r = boffL + s[t] - d;
        rowptr[i] = r;
        cursor[i] = r;
        if (i == n - 1) rowptr[n] = r + d;
    }
}

// CSR fill + GAT1 edge-weight precompute (4 heads). Atomic-latency-bound.
__global__ void fill_edges(const int* __restrict__ ei, int E, int n, int* cursor,
                           int* __restrict__ col, float* __restrict__ ew4,
                           const float* __restrict__ als1, const float* __restrict__ ald1) {
    int i = blockIdx.x * blockDim.x + threadIdx.x;
    int tot = E + n;
    if (i < tot) {
        int src, dst;
        if (i < E) { src = ei[i]; dst = ei[E + i]; }
        else { src = i - E; dst = i - E; }
        int pos = atomicAdd(&cursor[dst], 1);
        col[pos] = src;
        float4 as = ((const float4*)als1)[src];
        float4 ad = ((const float4*)ald1)[dst];
        float4 w;
        w.x = __expf(leaky(as.x + ad.x));
        w.y = __expf(leaky(as.y + ad.y));
        w.z = __expf(leaky(as.z + ad.z));
        w.w = __expf(leaky(as.w + ad.w));
        ((float4*)ew4)[pos] = w;
    }
}

// ---------------- FUSED: GAT1 x-space aggregate + W1 MFMA + W2 MFMA --------
// Aggregation commutes with the linear W1 transform:
//   sum_e alpha[e,h] * (x[s_e]@W1)[h-block] == (sum_e alpha[e,h]*x[s_e]) @ W1[h]
// Phase 1: per dst, aggregate x (bf16, 64 B/edge - L2-resident 1.25 MB buffer)
//   into aggx[4h][32]. Lane = (h=lane>>4, chpair=lane&15): the per-lane
//   accumulator IS the final value - zero reduction shuffles.
// Phase 2: 4 head-block GEMMs [16x32]@[32x64] via MFMA against W1p; relu+b1;
//   rows land in xs (the W2 staging LDS).
// Phase 3: out1[16,256] @ W2p -> h2 + GAT2 logits (unchanged).
__global__ __launch_bounds__(512) void gat1_agg_mfma(
        const unsigned* __restrict__ xbu,
        const float* __restrict__ ew4,
        const int* __restrict__ rowptr, const int* __restrict__ col,
        const float* __restrict__ b1,
        const unsigned short* __restrict__ W1p,
        const unsigned short* __restrict__ W2p,
        const float* __restrict__ asr, const float* __restrict__ adt,
        __hip_bfloat16* __restrict__ h2b,
        float* __restrict__ als, float* __restrict__ ald, int n) {
    __shared__ unsigned short xs[16 * 264];
    __shared__ unsigned short agx[16 * 136];   // [node][h*32+ch] bf16, stride 136
    __shared__ float aps[4][16];
    __shared__ float apd[4][16];
    int t = threadIdx.x;              // 512 = 8 waves
    int w = t >> 6, lane = t & 63;
    int base = blockIdx.x * 16;

    // ---- phase 1: x-space aggregation, 2 dsts per wave ----
    {
        int h = lane >> 4, cp = lane & 15;
        for (int rep = 0; rep < 2; rep++) {
            int r = w * 2 + rep;
            int dst = base + r;
            if (dst < n) {
                int start = rowptr[dst], end = rowptr[dst + 1];
                float a0 = 0.f, a1 = 0.f, ws = 0.f;
                for (int ib = start; ib < end; ib += 4) {
                    float lo[4], hi[4], wv[4];
#pragma unroll
                    for (int u = 0; u < 4; u++) {
                        int i = ib + u;
                        bool vld = i < end;
                        int s = vld ? col[i] : 0;
                        wv[u] = vld ? ew4[i * 4 + h] : 0.f;
                        unsigned xv = xbu[(size_t)s * 16 + cp];
                        unpack2(xv, lo[u], hi[u]);
                    }
#pragma unroll
                    for (int u = 0; u < 4; u++) {
                        a0 += lo[u] * wv[u];
                        a1 += hi[u] * wv[u];
                        ws += wv[u];
                    }
                }
                float inv = 1.0f / (ws + 1e-16f);
                unsigned short p0 = f2bf(a0 * inv), p1 = f2bf(a1 * inv);
                *(unsigned*)(agx + r * 136 + h * 32 + cp * 2) =
                    ((unsigned)p1 << 16) | p0;
            } else {
                *(unsigned*)(agx + r * 136 + h * 32 + cp * 2) = 0u;
            }
        }
    }
    __syncthreads();

    // ---- phase 2: per-head [16x32]@[32x64] MFMA -> relu -> xs ----
    if (w < 4) {
        int h = w;
        int mm = lane & 15, quad = lane >> 4;
        bf16x8 a = *((const bf16x8*)(agx + mm * 136 + h * 32 + quad * 8));
#pragma unroll
        for (int nt = 0; nt < 4; nt++) {
            bf16x8 bfr = *((const bf16x8*)(W1p + (h * 4 + nt) * 512 + lane * 8));
            floatx4 c = {0.f, 0.f, 0.f, 0.f};
            c = __builtin_amdgcn_mfma_f32_16x16x32_bf16(a, bfr, c, 0, 0, 0);
            int ch = h * 64 + nt * 16 + mm;
            float bb = b1[ch];
#pragma unroll
            for (int q = 0; q < 4; q++) {
                int node = quad * 4 + q;
                xs[node * 264 + ch] = f2bf(fmaxf(c[q] + bb, 0.f));
            }
        }
    }
    __syncthreads();

    // ---- phase 3: MFMA out1[16,256] @ W2p -> h2 + logits (waves 0-3) ----
    if (w < 4) {
        int m = lane & 15, quad = lane >> 4;
        floatx4 acc = {0.f, 0.f, 0.f, 0.f};
#pragma unroll
        for (int kt = 0; kt < 8; kt++) {
            bf16x8 a = *((const bf16x8*)(xs + m * 264 + kt * 32 + quad * 8));
            bf16x8 b = *((const bf16x8*)(W2p + (w * 8 + kt) * 512 + lane * 8));
            acc = __builtin_amdgcn_mfma_f32_16x16x32_bf16(a, b, acc, 0, 0, 0);
        }
        int colg = w * 16 + m;
        float a_s = asr[colg], a_d = adt[colg];
        float ps[4], pd[4];
#pragma unroll
        for (int q = 0; q < 4; q++) {
            int node = base + quad * 4 + q;
            if (node < n) h2b[(size_t)node * 64 + colg] = __float2bfloat16(acc[q]);
            ps[q] = acc[q] * a_s;
            pd[q] = acc[q] * a_d;
#pragma unroll
            for (int off = 1; off <= 8; off <<= 1) {
                ps[q] += __shfl_xor(ps[q], off);
                pd[q] += __shfl_xor(pd[q], off);
            }
            if (m == 0) {
                aps[w][quad * 4 + q] = ps[q];
                apd[w][quad * 4 + q] = pd[q];
            }
        }
    }
    __syncthreads();
    if (t < 16 && base + t < n) {
        als[base + t] = aps[0][t] + aps[1][t] + aps[2][t] + aps[3][t];
        ald[base + t] = apd[0][t] + apd[1][t] + apd[2][t] + apd[3][t];
    }
}

// wave per dst; GAT2 aggregate FUSED with GCN transform; 2x unrolled loop.
__global__ void gat2_agg_gcn(const unsigned short* __restrict__ h2b,
                             const float* __restrict__ als2,
                             const float* __restrict__ ald2,
                             const int* __restrict__ rowptr,
                             const int* __restrict__ col, const float* __restrict__ b2,
                             const float* __restrict__ Wg,
                             float* __restrict__ h3, int n) {
    __shared__ float WgL[64 * 32];     // 8 KB
    __shared__ float h2L[4][64];       // 1 KB, per-wave slot
    int t = threadIdx.x;
    for (int i = t; i < 64 * 32; i += 256) WgL[i] = Wg[i];
    __syncthreads();

    int w = t >> 6, lane = t & 63;
    int dst = blockIdx.x * 4 + w;
    if (dst >= n) return;
    int start = rowptr[dst], end = rowptr[dst + 1];
    float a_d = ald2[dst];

    int eg = lane >> 3;
    int cl = lane & 7;
    float acc[8];
#pragma unroll
    for (int j = 0; j < 8; j++) acc[j] = 0.f;
    float wsum = 0.f;
    for (int ib = start; ib < end; ib += 16) {
        int i0 = ib + eg, i1 = ib + 8 + eg;
        float w0 = 0.f, w1 = 0.f;
        int s0 = 0, s1 = 0;
        if (i0 < end) { s0 = col[i0]; w0 = __expf(leaky(als2[s0] + a_d)); }
        if (i1 < end) { s1 = col[i1]; w1 = __expf(leaky(als2[s1] + a_d)); }
        uint4 hv0 = *((const uint4*)(h2b + (size_t)s0 * 64) + cl);
        uint4 hv1 = *((const uint4*)(h2b + (size_t)s1 * 64) + cl);
        wsum += w0 + w1;
        float l0, u0, l1, u1, l2, u2, l3, u3;
        unpack2(hv0.x, l0, u0); unpack2(hv0.y, l1, u1);
        unpack2(hv0.z, l2, u2); unpack2(hv0.w, l3, u3);
        acc[0] += l0 * w0; acc[1] += u0 * w0;
        acc[2] += l1 * w0; acc[3] += u1 * w0;
        acc[4] += l2 * w0; acc[5] += u2 * w0;
        acc[6] += l3 * w0; acc[7] += u3 * w0;
        unpack2(hv1.x, l0, u0); unpack2(hv1.y, l1, u1);
        unpack2(hv1.z, l2, u2); unpack2(hv1.w, l3, u3);
        acc[0] += l0 * w1; acc[1] += u0 * w1;
        acc[2] += l1 * w1; acc[3] += u1 * w1;
        acc[4] += l2 * w1; acc[5] += u2 * w1;
        acc[6] += l3 * w1; acc[7] += u3 * w1;
    }
#pragma unroll
    for (int off = 8; off <= 32; off <<= 1) {
        wsum += __shfl_xor(wsum, off);
#pragma unroll
        for (int j = 0; j < 8; j++) acc[j] += __shfl_xor(acc[j], off);
    }
    float inv = 1.0f / (wsum + 1e-16f);
    if (lane < 8) {
        const float* bb = b2 + cl * 8;
#pragma unroll
        for (int j = 0; j < 8; j++)
            h2L[w][cl * 8 + j] = fmaxf(acc[j] * inv + bb[j], 0.f);
    }
    if (lane < 32) {
        float s0 = 0.f, s1 = 0.f;
#pragma unroll
        for (int k = 0; k < 64; k += 2) {
            s0 += h2L[w][k]     * WgL[k * 32 + lane];
            s1 += h2L[w][k + 1] * WgL[(k + 1) * 32 + lane];
        }
        h3[(size_t)dst * 32 + lane] = s0 + s1;
    }
}

// wave per dst; GCN aggregate FUSED with mean-pool accumulation; 2x unrolled.
__global__ void gcn_agg_pool(const float* __restrict__ h3, const float* __restrict__ dinv,
                             const int* __restrict__ rowptr, const int* __restrict__ col,
                             const float* __restrict__ bg, const int* __restrict__ batch,
                             float* __restrict__ pooled, int n) {
    __shared__ float rowL[4][32];
    __shared__ int gL[4];
    int t = threadIdx.x;
    int w = t >> 6, lane = t & 63;
    int dst = blockIdx.x * 4 + w;
    bool act = dst < n;
    if (act) {
        int start = rowptr[dst], end = rowptr[dst + 1];
        float dv = dinv[dst];
        int eg = lane >> 3;
        int cl = lane & 7;
        float4 acc = make_float4(0.f, 0.f, 0.f, 0.f);
        for (int ib = start; ib < end; ib += 16) {
            int i0 = ib + eg, i1 = ib + 8 + eg;
            float n0 = 0.f, n1 = 0.f;
            int s0 = 0, s1 = 0;
            if (i0 < end) { s0 = col[i0]; n0 = dinv[s0] * dv; }
            if (i1 < end) { s1 = col[i1]; n1 = dinv[s1] * dv; }
            float4 hv0 = ((const float4*)(h3 + (size_t)s0 * 32))[cl];
            float4 hv1 = ((const float4*)(h3 + (size_t)s1 * 32))[cl];
            acc.x += hv0.x * n0; acc.y += hv0.y * n0;
            acc.z += hv0.z * n0; acc.w += hv0.w * n0;
            acc.x += hv1.x * n1; acc.y += hv1.y * n1;
            acc.z += hv1.z * n1; acc.w += hv1.w * n1;
        }
#pragma unroll
        for (int off = 8; off <= 32; off <<= 1) {
            acc.x += __shfl_xor(acc.x, off);
            acc.y += __shfl_xor(acc.y, off);
            acc.z += __shfl_xor(acc.z, off);
            acc.w += __shfl_xor(acc.w, off);
        }
        if (lane == 0) gL[w] = batch[dst];
        if (lane < 8) {
            int cl2 = lane & 7;
            float4 bb = ((const float4*)bg)[cl2];
            float4 o;
            o.x = fmaxf(acc.x + bb.x, 0.f);
            o.y = fmaxf(acc.y + bb.y, 0.f);
            o.z = fmaxf(acc.z + bb.z, 0.f);
            o.w = fmaxf(acc.w + bb.w, 0.f);
            *((float4*)&rowL[w][cl2 * 4]) = o;
        }
    } else if (lane == 0) {
        gL[w] = -1;
    }
    __syncthreads();
    if (t < 32) {
        float cur = 0.f; int curg = -1;
#pragma unroll
        for (int r = 0; r < 4; r++) {
            int g = gL[r];
            if (g < 0) continue;
            float v = rowL[r][t];
            if (g == curg) cur += v;
            else {
                if (curg >= 0) atomicAdd(&pooled[curg * 32 + t], cur);
                curg = g; cur = v;
            }
        }
        if (curg >= 0) atomicAdd(&pooled[curg * 32 + t], cur);
    }
}

// ---------------- head: pooled sums -> mean -> anomaly[64] + emb[64,64] ----
__device__ __forceinline__ int lbound(const int* __restrict__ b, int n, int key) {
    int lo = 0, hi = n;
    while (lo < hi) { int m = (lo + hi) >> 1; if (b[m] < key) lo = m + 1; else hi = m; }
    return lo;
}

__global__ void head_kernel(const float* __restrict__ pooled_s,
                            const int* __restrict__ batch, int n,
                            const float* __restrict__ A1, const float* __restrict__ ba1,
                            const float* __restrict__ A2, const float* __restrict__ ba2,
                            const float* __restrict__ A3, const float* __restrict__ ba3,
                            const float* __restrict__ Wemb, const float* __restrict__ bemb,
                            float* __restrict__ out) {
    __shared__ float P[64 * 32];
    __shared__ float Z1[64 * 32];
    __shared__ float Z2[64 * 16];
    __shared__ int cntL[64];
    int t = threadIdx.x;
    if (t < 64) cntL[t] = lbound(batch, n, t + 1) - lbound(batch, n, t);
    __syncthreads();
    for (int i = t; i < 64 * 32; i += 256) {
        int g = i >> 5;
        P[i] = pooled_s[i] / fmaxf((float)cntL[g], 1.0f);
    }
    __syncthreads();
    for (int i = t; i < 64 * 32; i += 256) {
        int g = i >> 5, c = i & 31;
        float a = ba1[c];
#pragma unroll
        for (int k = 0; k < 32; k++) a += P[g * 32 + k] * A1[k * 32 + c];
        Z1[i] = a > 0.f ? a : 0.f;
    }
    __syncthreads();
    for (int i = t; i < 64 * 16; i += 256) {
        int g = i >> 4, c = i & 15;
        float a = ba2[c];
#pragma unroll
        for (int k = 0; k < 32; k++) a += Z1[g * 32 + k] * A2[k * 16 + c];
        Z2[i] = a > 0.f ? a : 0.f;
    }
    __syncthreads();
    for (int g = t; g < 64; g += 256) {
        float a = ba3[0];
#pragma unroll
        for (int k = 0; k < 16; k++) a += Z2[g * 16 + k] * A3[k];
        out[g] = 1.0f / (1.0f + expf(-a));
    }
    for (int i = t; i < 64 * 64; i += 256) {
        int g = i >> 6, c = i & 63;
        float a = bemb[c];
#pragma unroll
        for (int k = 0; k < 32; k++) a += P[g * 32 + k] * Wemb[k * 64 + c];
        out[64 + i] = tanhf(a);
    }
}

extern "C" void kernel_launch(void* const* d_in, const int* in_sizes, int n_in,
                              void* d_out, int out_size, void* d_ws, size_t ws_size,
                              hipStream_t stream) {
    const float* x    = (const float*)d_in[0];
    const int*   ei   = (const int*)d_in[1];
    const int*   batch= (const int*)d_in[2];
    const float* W1   = (const float*)d_in[3];
    const float* as1  = (const float*)d_in[4];
    const float* ad1  = (const float*)d_in[5];
    const float* b1   = (const float*)d_in[6];
    const float* W2   = (const float*)d_in[7];
    const float* as2  = (const float*)d_in[8];
    const float* ad2  = (const float*)d_in[9];
    const float* b2   = (const float*)d_in[10];
    const float* Wg   = (const float*)d_in[11];
    const float* bg   = (const float*)d_in[12];
    const float* A1   = (const float*)d_in[13];
    const float* ba1  = (const float*)d_in[14];
    const float* A2   = (const float*)d_in[15];
    const float* ba2  = (const float*)d_in[16];
    const float* A3   = (const float*)d_in[17];
    const float* ba3  = (const float*)d_in[18];
    const float* Wemb = (const float*)d_in[19];
    const float* bemb = (const float*)d_in[20];
    float* out = (float*)d_out;

    const int N = in_sizes[0] / 32;
    const int E = in_sizes[1] / 2;
    const int ET = E + N;

    char* base = (char*)d_ws;
    size_t off = 0;
    auto take = [&](size_t bytes) -> char* {
        char* p = base + off;
        off = (off + bytes + 255) & ~(size_t)255;
        return p;
    };
    int*   deg    = (int*)take((size_t)N * 4);
    int*   rowptr = (int*)take((size_t)(N + 1) * 4);
    int*   cursor = (int*)take((size_t)N * 4);
    int*   col    = (int*)take((size_t)ET * 4);
    float* ew4    = (float*)take((size_t)ET * 16);
    float* dinv   = (float*)take((size_t)N * 4);
    float* als1   = (float*)take((size_t)N * 16);   // node-major [n][4]
    float* ald1   = (float*)take((size_t)N * 16);
    int*   bsum   = (int*)take(256 * 4);
    unsigned short* W2p = (unsigned short*)take(32 * 512 * 2);
    unsigned short* W1p = (unsigned short*)take(16 * 512 * 2);
    unsigned* xbu = (unsigned*)take((size_t)N * 64);      // bf16 x rows
    __hip_bfloat16* h2b = (__hip_bfloat16*)take((size_t)N * 128);
    float* als2 = (float*)take((size_t)N * 4);
    float* ald2 = (float*)take((size_t)N * 4);
    float* h3   = (float*)take((size_t)N * 128);
    float* pooled = (float*)take(64 * 32 * 4);

    int gN = (N + 255) / 256;
    int gE = (ET + 255) / 256;
    int gN4 = (N + 3) / 4;
    int gN16 = (N + 15) / 16;
    int gT = (N + 63) / 64;
    int gZ = (N + 255) / 256;
    int gPre = gT + gZ + 1;

    prelude<<<gPre, 256, 0, stream>>>(x, W1, as1, ad1, W2, xbu, als1, ald1,
                                      W2p, W1p, deg, pooled, N, gT, gZ);
    count_edges<<<gE, 256, 0, stream>>>(ei, E, N, deg);
    deg_dinv_bsum<<<gN, 256, 0, stream>>>(deg, dinv, bsum, N);
    write_rowptr<<<gN, 256, 0, stream>>>(deg, bsum, rowptr, cursor, gN, N);
    fill_edges<<<gE, 256, 0, stream>>>(ei, E, N, cursor, col, ew4, als1, ald1);

    gat1_agg_mfma<<<gN16, 512, 0, stream>>>(xbu, ew4, rowptr, col, b1,
                                            W1p, W2p, as2, ad2,
                                            h2b, als2, ald2, N);

    gat2_agg_gcn<<<gN4, 256, 0, stream>>>((const unsigned short*)h2b, als2, ald2,
                                          rowptr, col, b2, Wg, h3, N);
    gcn_agg_pool<<<gN4, 256, 0, stream>>>(h3, dinv, rowptr, col, bg, batch,
                                          pooled, N);
    head_kernel<<<1, 256, 0, stream>>>(pooled, batch, N, A1, ba1, A2, ba2, A3, ba3,
                                       Wemb, bemb, out);
}